// Round 7
// baseline (13250.006 us; speedup 1.0000x reference)
//
#include <hip/hip_runtime.h>
#include <hip/hip_bf16.h>
#include <cstdint>
#include <cstddef>

#define DEV __device__ __forceinline__

static constexpr int D  = 768;
static constexpr int NH = 12;
static constexpr int NE = 4;
static constexpr int DH = 3072;
static constexpr int L  = 1024;
static constexpr int T  = 2048;
static constexpr int V  = 32000;
static constexpr int NL = 4;

// ------------------------------------------------------------- fp32 GEMM ----
// C[M,N] = A[M,K] @ B[K,N] (+bias), all fp32, B native [K][N].
// 128x128 tile, BK=16, 256 threads, 8x8 microtile (4+4 split rows/cols),
// double-buffered LDS with register prefetch. NO XCD swizzle (r6 A/B showed
// it blows L2 reuse 5x on these small-grid, L3-resident GEMMs).
// Per-z: A += z*aOff, B += z*bOff, out col += z*zCol, bias[z*zBias + local].
// EPI: 0 = store; 1 = qkv (elu+1 for col<1536); 2 = out += acc+bias;
// 3 = srow[m][z] * gelu(acc+bias); 4 = atomicAdd (no bias).
template <int EPI>
__global__ __launch_bounds__(256, 4) void k_fgemm(
    const float* __restrict__ A, int lda, long aOff,
    const float* __restrict__ B, int ldb, long bOff,
    const float* __restrict__ bias, int zBias,
    float* __restrict__ outp, int ldc, int zCol,
    const float* __restrict__ aux, int Keff) {
  const int z = blockIdx.z;
  A += (size_t)z * (size_t)aOff;
  B += (size_t)z * (size_t)bOff;

  const int m0 = blockIdx.y * 128;
  const int n0 = blockIdx.x * 128;

  const int tid = threadIdx.x;
  const int tx = tid & 15, ty = tid >> 4;
  // staging coords
  const int ar = tid >> 2;        // A row 0..63 (and +64)
  const int ak = (tid & 3) * 4;   // A k sub 0,4,8,12
  const int bk = tid >> 4;        // B k row 0..15
  const int bn = (tid & 15) * 8;  // B col 0..120

  const float* Ap  = A + (size_t)(m0 + ar) * lda + ak;
  const float* Ap2 = Ap + (size_t)64 * lda;
  const float* Bp  = B + (size_t)bk * ldb + n0 + bn;

  __shared__ float As[2][16][132];
  __shared__ float Bs[2][16][132];

  float acc[8][8];
#pragma unroll
  for (int i = 0; i < 8; ++i)
#pragma unroll
    for (int j = 0; j < 8; ++j) acc[i][j] = 0.f;

  float4 pa0, pa1, pb0, pb1;

  auto LOADR = [&](int kt) {
    pa0 = *(const float4*)(Ap + kt);
    pa1 = *(const float4*)(Ap2 + kt);
    const float* bb = Bp + (size_t)kt * ldb;
    pb0 = *(const float4*)(bb);
    pb1 = *(const float4*)(bb + 4);
  };
  auto STORE = [&](int buf) {
    As[buf][ak + 0][ar] = pa0.x;
    As[buf][ak + 1][ar] = pa0.y;
    As[buf][ak + 2][ar] = pa0.z;
    As[buf][ak + 3][ar] = pa0.w;
    As[buf][ak + 0][64 + ar] = pa1.x;
    As[buf][ak + 1][64 + ar] = pa1.y;
    As[buf][ak + 2][64 + ar] = pa1.z;
    As[buf][ak + 3][64 + ar] = pa1.w;
    *(float4*)&Bs[buf][bk][bn] = pb0;
    *(float4*)&Bs[buf][bk][bn + 4] = pb1;
  };
  auto COMP = [&](int buf) {
#pragma unroll
    for (int kk = 0; kk < 16; ++kk) {
      const float4 aLo = *(const float4*)&As[buf][kk][ty * 4];
      const float4 aHi = *(const float4*)&As[buf][kk][64 + ty * 4];
      const float4 bLo = *(const float4*)&Bs[buf][kk][tx * 4];
      const float4 bHi = *(const float4*)&Bs[buf][kk][64 + tx * 4];
      const float av[8] = {aLo.x, aLo.y, aLo.z, aLo.w,
                           aHi.x, aHi.y, aHi.z, aHi.w};
      const float bv[8] = {bLo.x, bLo.y, bLo.z, bLo.w,
                           bHi.x, bHi.y, bHi.z, bHi.w};
#pragma unroll
      for (int i = 0; i < 8; ++i)
#pragma unroll
        for (int j = 0; j < 8; ++j) acc[i][j] += av[i] * bv[j];
    }
  };

  LOADR(0);
  STORE(0);
  __syncthreads();
  int buf = 0;
  for (int kt = 16; kt < Keff; kt += 16) {
    LOADR(kt);      // prefetch next tile (latency hidden under COMP)
    COMP(buf);
    STORE(buf ^ 1);
    __syncthreads();
    buf ^= 1;
  }
  COMP(buf);

  // ------------------------------------------------------------- epilogue --
#pragma unroll
  for (int jh = 0; jh < 2; ++jh) {
    const int cl = n0 + jh * 64 + tx * 4;  // local col
    const int cg = cl + z * zCol;          // global out col
    float4 bq = make_float4(0.f, 0.f, 0.f, 0.f);
    if constexpr (EPI != 4) bq = *(const float4*)&bias[(size_t)zBias * z + cl];
    const float bqa[4] = {bq.x, bq.y, bq.z, bq.w};
#pragma unroll
    for (int ih = 0; ih < 2; ++ih) {
#pragma unroll
      for (int i = 0; i < 4; ++i) {
        const int mm = m0 + ih * 64 + ty * 4 + i;
        float vv[4];
#pragma unroll
        for (int j = 0; j < 4; ++j) vv[j] = acc[ih * 4 + i][jh * 4 + j] + bqa[j];
        float* op = outp + (size_t)mm * ldc + cg;
        if constexpr (EPI == 0) {
          *(float4*)op = make_float4(vv[0], vv[1], vv[2], vv[3]);
        } else if constexpr (EPI == 1) {
#pragma unroll
          for (int j = 0; j < 4; ++j) {
            const float v = vv[j];
            op[j] = (cl + j < 1536) ? (v > 0.f ? v + 1.f : expf(v)) : v;
          }
        } else if constexpr (EPI == 2) {
#pragma unroll
          for (int j = 0; j < 4; ++j) op[j] += vv[j];
        } else if constexpr (EPI == 3) {
          const float s = aux[mm * 4 + z];
#pragma unroll
          for (int j = 0; j < 4; ++j) {
            const float v = vv[j];
            op[j] = s * (0.5f * v * (1.f + erff(v * 0.70710678118654752f)));
          }
        } else {
#pragma unroll
          for (int j = 0; j < 4; ++j) atomicAdd(op + j, vv[j]);
        }
      }
    }
  }
}

// ------------------------------------------------------------ small kernels --
__global__ void k_embed(const int* __restrict__ tok,
                        const float* __restrict__ emb,
                        const float* __restrict__ pos, float* __restrict__ x) {
  const int idx = blockIdx.x * 256 + threadIdx.x;  // exactly T*D
  const int t = idx / D, d = idx - t * D;
  const int tk = tok[t];
  x[idx] = emb[(size_t)tk * D + d] + pos[(size_t)(t & (L - 1)) * D + d];
}

// LayerNorm fp32->fp32. If gw != nullptr also emit fp32 gate logits (+gb).
__global__ __launch_bounds__(256) void k_ln(const float* __restrict__ x,
                                            const float* __restrict__ g,
                                            const float* __restrict__ bb,
                                            float* __restrict__ xn,
                                            const float* __restrict__ gw,
                                            const float* __restrict__ gb,
                                            float* __restrict__ glog) {
  const int row = blockIdx.x, tid = threadIdx.x;
  const float* xr = x + (size_t)row * D;
  const float v0 = xr[tid], v1 = xr[tid + 256], v2 = xr[tid + 512];
  float s = v0 + v1 + v2, s2 = v0 * v0 + v1 * v1 + v2 * v2;
  for (int off = 1; off < 64; off <<= 1) {
    s += __shfl_xor(s, off);
    s2 += __shfl_xor(s2, off);
  }
  __shared__ float rs[4], rs2[4];
  const int w = tid >> 6;
  if ((tid & 63) == 0) { rs[w] = s; rs2[w] = s2; }
  __syncthreads();
  const float S = rs[0] + rs[1] + rs[2] + rs[3];
  const float S2 = rs2[0] + rs2[1] + rs2[2] + rs2[3];
  const float mean = S * (1.f / 768.f);
  const float var = fmaxf(S2 * (1.f / 768.f) - mean * mean, 0.f);
  const float rstd = rsqrtf(var + 1e-5f);
  const float o0 = (v0 - mean) * rstd * g[tid]       + bb[tid];
  const float o1 = (v1 - mean) * rstd * g[tid + 256] + bb[tid + 256];
  const float o2 = (v2 - mean) * rstd * g[tid + 512] + bb[tid + 512];
  float* xo = xn + (size_t)row * D;
  xo[tid] = o0;
  xo[tid + 256] = o1;
  xo[tid + 512] = o2;

  if (gw != nullptr) {
    const float4 ga = *(const float4*)&gw[tid * 4];
    const float4 gbv = *(const float4*)&gw[(tid + 256) * 4];
    const float4 gc = *(const float4*)&gw[(tid + 512) * 4];
    float p0 = o0 * ga.x + o1 * gbv.x + o2 * gc.x;
    float p1 = o0 * ga.y + o1 * gbv.y + o2 * gc.y;
    float p2 = o0 * ga.z + o1 * gbv.z + o2 * gc.z;
    float p3 = o0 * ga.w + o1 * gbv.w + o2 * gc.w;
    for (int off = 1; off < 64; off <<= 1) {
      p0 += __shfl_xor(p0, off);
      p1 += __shfl_xor(p1, off);
      p2 += __shfl_xor(p2, off);
      p3 += __shfl_xor(p3, off);
    }
    __shared__ float rg[4][4];
    if ((tid & 63) == 0) {
      rg[w][0] = p0; rg[w][1] = p1; rg[w][2] = p2; rg[w][3] = p3;
    }
    __syncthreads();
    if (tid == 0) {
      float* gl = glog + (size_t)row * 4;
#pragma unroll
      for (int e = 0; e < 4; ++e)
        gl[e] = rg[0][e] + rg[1][e] + rg[2][e] + rg[3][e] + gb[e];
    }
  }
}

// top-2 + softmax over 4 gate logits -> srow[T][4]
__global__ void k_topk(const float* __restrict__ glog,
                       float* __restrict__ srow) {
  const int t = blockIdx.x * 256 + threadIdx.x;  // exactly T
  float gv[4];
#pragma unroll
  for (int i = 0; i < 4; ++i) gv[i] = glog[t * 4 + i];
  int i1 = 0;
#pragma unroll
  for (int i = 1; i < 4; ++i)
    if (gv[i] > gv[i1]) i1 = i;
  int i2 = -1;
#pragma unroll
  for (int i = 0; i < 4; ++i) {
    if (i == i1) continue;
    if (i2 < 0 || gv[i] > gv[i2]) i2 = i;
  }
  const float e = expf(gv[i2] - gv[i1]);
  const float wa = 1.f / (1.f + e), wb = e / (1.f + e);
  float o[4] = {0.f, 0.f, 0.f, 0.f};
  o[i1] = wa;
  o[i2] = wb;
#pragma unroll
  for (int i = 0; i < 4; ++i) srow[t * 4 + i] = o[i];
}

__global__ void k_cat3(const float* __restrict__ a, const float* __restrict__ b,
                       const float* __restrict__ c, float* __restrict__ o) {
  const int i = blockIdx.x * 256 + threadIdx.x;  // exactly 2304
  o[i] = i < 768 ? a[i] : (i < 1536 ? b[i - 768] : c[i - 1536]);
}

// wqkv[k][j] (768x2304) from qw/kw/vw (each 768x768), fp32
__global__ void k_catW(const float* __restrict__ qw,
                       const float* __restrict__ kw,
                       const float* __restrict__ vw, float* __restrict__ o) {
  const int idx = blockIdx.x * 256 + threadIdx.x;  // exactly 768*2304
  const int k = idx / 2304, j = idx - k * 2304;
  float v;
  if (j < 768) v = qw[k * 768 + j];
  else if (j < 1536) v = kw[k * 768 + (j - 768)];
  else v = vw[k * 768 + (j - 1536)];
  o[idx] = v;
}

// Partial KV/Z over an L-chunk of 128 rows. part[c][bh][e*64+f], Z at +4096.
__global__ __launch_bounds__(256) void k_kvpart(const float* __restrict__ qkv,
                                                float* __restrict__ part) {
  const int bh = blockIdx.x;  // 0..23
  const int b = bh / NH, h = bh % NH;
  const int c = blockIdx.y;  // 0..7
  const int tid = threadIdx.x;
  __shared__ float kf[64], vv[64];
  float acc[16];
#pragma unroll
  for (int j = 0; j < 16; ++j) acc[j] = 0.f;
  float zacc = 0.f;
  const int e = tid >> 2;
  const int f0 = (tid & 3) * 16;
  const int t0 = b * L + c * 128;
  for (int i = 0; i < 128; ++i) {
    __syncthreads();
    const size_t rowb = (size_t)(t0 + i) * 2304;
    if (tid < 64) kf[tid] = qkv[rowb + 768 + h * 64 + tid];
    else if (tid < 128) vv[tid - 64] = qkv[rowb + 1536 + h * 64 + (tid - 64)];
    __syncthreads();
    const float ke = kf[e];
#pragma unroll
    for (int j = 0; j < 16; ++j) acc[j] += ke * vv[f0 + j];
    if (tid < 64) zacc += kf[tid];
  }
  const size_t base = ((size_t)c * 24 + bh) * 4160;
#pragma unroll
  for (int j = 0; j < 16; ++j) part[base + e * 64 + f0 + j] = acc[j];
  if (tid < 64) part[base + 4096 + tid] = zacc;
}

__global__ void k_kvred(const float* __restrict__ part, float* __restrict__ kv) {
  const int idx = blockIdx.x * 256 + threadIdx.x;  // exactly 24*4160
  float s = 0.f;
#pragma unroll
  for (int cc = 0; cc < 8; ++cc) s += part[(size_t)cc * 99840 + idx];
  kv[idx] = s;
}

__global__ __launch_bounds__(256) void k_attnout(const float* __restrict__ qkv,
                                                 const float* __restrict__ kv,
                                                 float* __restrict__ att) {
  const int t = blockIdx.x;
  const int b = t >> 10;
  const int tid = threadIdx.x;
  __shared__ float q[768];
  __shared__ float den[12];
  for (int i = tid; i < 768; i += 256) q[i] = qkv[(size_t)t * 2304 + i];
  __syncthreads();
  if (tid < 12) {
    const float* zz = kv + ((size_t)(b * NH + tid)) * 4160 + 4096;
    float s = 0.f;
#pragma unroll
    for (int e = 0; e < 64; ++e) s += q[tid * 64 + e] * zz[e];
    den[tid] = s + 1e-6f;
  }
  __syncthreads();
  for (int i = tid; i < 768; i += 256) {
    const int h = i >> 6, f = i & 63;
    const float* Kv = kv + ((size_t)(b * NH + h)) * 4160;
    float s = 0.f;
#pragma unroll
    for (int e = 0; e < 64; ++e) s += q[h * 64 + e] * Kv[e * 64 + f];
    att[(size_t)t * 768 + i] = s / den[h];
  }
}

// x += sum_e srow[t][e] * b2[e][n]
__global__ void k_moebias(float* __restrict__ x, const float* __restrict__ srow,
                          const float* __restrict__ b2l) {
  const int idx = blockIdx.x * 256 + threadIdx.x;  // exactly T*D
  const int t = idx / D, n = idx - t * D;
  const float* s = srow + t * 4;
  x[idx] += s[0] * b2l[n] + s[1] * b2l[D + n] + s[2] * b2l[2 * D + n] +
            s[3] * b2l[3 * D + n];
}

// ------------------------------------------------------------------ launch ---
extern "C" void kernel_launch(void* const* d_in, const int* in_sizes, int n_in,
                              void* d_out, int out_size, void* d_ws,
                              size_t ws_size, hipStream_t stream) {
  const int*   tokens = (const int*)d_in[0];
  const float* emb  = (const float*)d_in[1];
  const float* pos  = (const float*)d_in[2];
  const float* qw   = (const float*)d_in[3];
  const float* qb   = (const float*)d_in[4];
  const float* kw   = (const float*)d_in[5];
  const float* kb   = (const float*)d_in[6];
  const float* vw   = (const float*)d_in[7];
  const float* vb   = (const float*)d_in[8];
  const float* ow   = (const float*)d_in[9];
  const float* ob   = (const float*)d_in[10];
  const float* ln1g = (const float*)d_in[11];
  const float* ln1b = (const float*)d_in[12];
  const float* ln2g = (const float*)d_in[13];
  const float* ln2b = (const float*)d_in[14];
  const float* gw   = (const float*)d_in[15];
  const float* gb   = (const float*)d_in[16];
  const float* w1   = (const float*)d_in[17];
  const float* b1   = (const float*)d_in[18];
  const float* w2   = (const float*)d_in[19];
  const float* b2   = (const float*)d_in[20];
  const float* hw   = (const float*)d_in[21];
  const float* hb   = (const float*)d_in[22];

  char* p = (char*)d_ws;
  auto alloc = [&](size_t bytes) -> void* {
    void* r = (void*)p;
    p += (bytes + 255) & ~((size_t)255);
    return r;
  };
  float* x    = (float*)alloc((size_t)T * D * 4);          // 6.3 MB
  float* xn   = (float*)alloc((size_t)T * D * 4);          // 6.3 MB
  float* qkvb = (float*)alloc((size_t)T * 2304 * 4);       // 18.9 MB
  float* att  = (float*)alloc((size_t)T * D * 4);          // 6.3 MB
  float* kvp  = (float*)alloc((size_t)8 * 24 * 4160 * 4);  // 3.2 MB
  float* kv   = (float*)alloc((size_t)24 * 4160 * 4);      // 0.4 MB
  float* srow = (float*)alloc((size_t)T * 4 * 4);
  float* glog = (float*)alloc((size_t)T * 4 * 4);
  float* bqkv = (float*)alloc((size_t)2304 * 4);
  float* wqkv = (float*)alloc((size_t)D * 2304 * 4);       // 7.1 MB
  // hs [T][12288] fp32 = 100.7 MB lives in d_out (262 MB), overwritten by the
  // final head GEMM afterwards.
  float* hs = (float*)d_out;

  k_embed<<<dim3(6144), 256, 0, stream>>>(tokens, emb, pos, x);

  for (int l = 0; l < NL; ++l) {
    const size_t DD = (size_t)D * D;
    k_catW<<<dim3(6912), 256, 0, stream>>>(qw + l * DD, kw + l * DD,
                                           vw + l * DD, wqkv);
    k_cat3<<<dim3(9), 256, 0, stream>>>(qb + l * D, kb + l * D, vb + l * D,
                                        bqkv);

    // attention
    k_ln<<<dim3(T), 256, 0, stream>>>(x, ln1g + l * D, ln1b + l * D, xn,
                                      nullptr, nullptr, nullptr);
    k_fgemm<1><<<dim3(18, 16, 1), 256, 0, stream>>>(
        xn, D, 0, wqkv, 2304, 0, bqkv, 0, qkvb, 2304, 0, nullptr, D);
    k_kvpart<<<dim3(24, 8), 256, 0, stream>>>(qkvb, kvp);
    k_kvred<<<dim3(390), 256, 0, stream>>>(kvp, kv);
    k_attnout<<<dim3(T), 256, 0, stream>>>(qkvb, kv, att);
    k_fgemm<2><<<dim3(6, 16, 1), 256, 0, stream>>>(
        att, D, 0, ow + l * DD, D, 0, ob + l * D, 0, x, D, 0, nullptr, D);

    // MoE
    k_ln<<<dim3(T), 256, 0, stream>>>(x, ln2g + l * D, ln2b + l * D, xn,
                                      gw + (size_t)l * D * NE, gb + l * NE,
                                      glog);
    k_topk<<<dim3(8), 256, 0, stream>>>(glog, srow);
    k_fgemm<3><<<dim3(24, 16, 4), 256, 0, stream>>>(
        xn, D, 0, w1 + (size_t)l * NE * D * DH, DH, (long)D * DH,
        b1 + (size_t)l * NE * DH, DH, hs, 12288, DH, srow, D);
    k_moebias<<<dim3(6144), 256, 0, stream>>>(x, srow,
                                              b2 + (size_t)l * NE * D);
    // w2 as one [2048x12288]@[12288x768] GEMM, split-K by 8 (atomicAdd into x)
    k_fgemm<4><<<dim3(6, 16, 8), 256, 0, stream>>>(
        hs, 12288, 1536, w2 + (size_t)l * NE * DH * D, D, (long)1536 * D,
        nullptr, 0, x, D, 0, nullptr, 1536);
  }

  // head: d_out = x @ hw + hb (hs scratch region is dead by now)
  k_fgemm<0><<<dim3(250, 16, 1), 256, 0, stream>>>(
      x, D, 0, hw, V, 0, hb, 0, (float*)d_out, V, 0, nullptr, D);
}

// Round 8
// 6875.787 us; speedup vs baseline: 1.9271x; 1.9271x over previous
//
#include <hip/hip_runtime.h>
#include <hip/hip_bf16.h>
#include <cstdint>
#include <cstddef>

typedef __hip_bfloat16 bf16;
typedef __attribute__((ext_vector_type(8))) short bf16x8;
typedef __attribute__((ext_vector_type(4))) float f32x4;

#define DEV __device__ __forceinline__

static constexpr int D  = 768;
static constexpr int NH = 12;
static constexpr int NE = 4;
static constexpr int DH = 3072;
static constexpr int L  = 1024;
static constexpr int T  = 2048;
static constexpr int V  = 32000;
static constexpr int NL = 4;

DEV bf16 f2b(float f) { return __float2bfloat16(f); }
DEV unsigned short f2bu(float f) {
  bf16 b = f2b(f);
  return *reinterpret_cast<unsigned short*>(&b);
}

// ---------------------------------------------------------------- staging ----
DEV void gld16(const void* g, short* ldsbase, int lane) {
#if __has_builtin(__builtin_amdgcn_global_load_lds)
  (void)lane;
  __builtin_amdgcn_global_load_lds(
      (const __attribute__((address_space(1))) unsigned int*)g,
      (__attribute__((address_space(3))) unsigned int*)ldsbase, 16, 0, 0);
#else
  *reinterpret_cast<bf16x8*>(ldsbase + lane * 8) =
      *reinterpret_cast<const bf16x8*>(g);
#endif
}

// ------------------------------------------------------------- fp32 GEMM ----
// r5-exact kernel (proven 7942us total): C[M,N] = A[M,K]@B[K,N] (+bias), all
// fp32, B native [K][N]. 128x128 tile, BK=16, 256 threads, 8x8 microtile,
// single-buffer LDS (lockstep K-march keeps L2 working set = one k-slice;
// r6/r7 dbuf variant thrashed L2: FETCH x5, VALUBusy 64->17).
// EPI: 0 = store; 1 = qkv (elu+1 for col<1536); 2 = out += acc+bias;
// 3 = srow[m][z] * gelu(acc+bias); 4 = atomicAdd (no bias).
template <int EPI>
__global__ __launch_bounds__(256) void k_fgemm(
    const float* __restrict__ A, int lda, long aOff,
    const float* __restrict__ B, int ldb, long bOff,
    const float* __restrict__ bias, int zBias,
    float* __restrict__ outp, int ldc, int zCol,
    const float* __restrict__ aux,
    int N, int Keff) {
  const int z = blockIdx.z;
  A += (size_t)z * (size_t)aOff;
  B += (size_t)z * (size_t)bOff;
  const int tid = threadIdx.x;
  const int tx = tid & 15;        // n-block
  const int ty = tid >> 4;        // m-block
  const int m0 = blockIdx.y * 128;
  const int n0 = blockIdx.x * 128;
  const int colBase = n0 + z * zCol;

  __shared__ float As[16 * 132];  // [kk][m], row stride 132
  __shared__ float Bs[16 * 132];  // [kk][n]

  float acc[8][8];
#pragma unroll
  for (int i = 0; i < 8; ++i)
#pragma unroll
    for (int j = 0; j < 8; ++j) acc[i][j] = 0.f;

  const int sk = tid & 15;   // k index for A staging
  const int sm = tid >> 4;   // m base for A staging

  for (int kt = 0; kt < Keff; kt += 16) {
    __syncthreads();
#pragma unroll
    for (int i = 0; i < 8; ++i) {
      const int m = sm + 16 * i;
      As[sk * 132 + m] = A[(size_t)(m0 + m) * lda + kt + sk];
    }
#pragma unroll
    for (int i = 0; i < 8; ++i) {
      const int idx = tid + 256 * i;
      const int kk = idx >> 7, n = idx & 127;
      Bs[kk * 132 + n] = B[(size_t)(kt + kk) * ldb + n0 + n];
    }
    __syncthreads();

#pragma unroll
    for (int kk = 0; kk < 16; ++kk) {
      const float4 a0 = *(const float4*)&As[kk * 132 + ty * 8];
      const float4 a1 = *(const float4*)&As[kk * 132 + ty * 8 + 4];
      const float4 b0 = *(const float4*)&Bs[kk * 132 + tx * 8];
      const float4 b1 = *(const float4*)&Bs[kk * 132 + tx * 8 + 4];
      const float av[8] = {a0.x, a0.y, a0.z, a0.w, a1.x, a1.y, a1.z, a1.w};
      const float bv[8] = {b0.x, b0.y, b0.z, b0.w, b1.x, b1.y, b1.z, b1.w};
#pragma unroll
      for (int i = 0; i < 8; ++i)
#pragma unroll
        for (int j = 0; j < 8; ++j) acc[i][j] += av[i] * bv[j];
    }
  }

#pragma unroll
  for (int j = 0; j < 8; ++j) {
    const int col = colBase + tx * 8 + j;
    float bvl = 0.f;
    if constexpr (EPI != 4) bvl = bias[zBias * z + col];
#pragma unroll
    for (int i = 0; i < 8; ++i) {
      const int mm = m0 + ty * 8 + i;
      float v = acc[i][j] + bvl;
      const size_t idx = (size_t)mm * ldc + col;
      if constexpr (EPI == 0) {
        outp[idx] = v;
      } else if constexpr (EPI == 1) {
        outp[idx] = (col < 1536) ? (v > 0.f ? v + 1.f : expf(v)) : v;
      } else if constexpr (EPI == 2) {
        outp[idx] += v;
      } else if constexpr (EPI == 3) {
        const float s  = aux[mm * 4 + z];
        const float gl = 0.5f * v * (1.f + erff(v * 0.70710678118654752f));
        outp[idx] = s * gl;
      } else {
        atomicAdd(outp + idx, v);
      }
    }
  }
}

// ----------------------------------------------------- bf16 MFMA head GEMM --
// C[M,Nh] fp32 = A[M,768]bf16 @ BT[Nh,768]bf16^T + bias. 128x128 tile, BK=32,
// 4 waves, 4x4 frags of mfma_f32_16x16x32_bf16 (fragment layout per verified
// m91/m92 ladder: A/B lane&15=row, k=(lane>>4)*8+j; C/D col=lane&15,
// row=(lane>>4)*4+reg). Head feeds no router gate -> bf16-safe.
__global__ __launch_bounds__(256) void k_bgemm(
    const bf16* __restrict__ A, const bf16* __restrict__ BT,
    const float* __restrict__ bias, float* __restrict__ outp,
    int ldc, int Keff) {
  const int tid  = threadIdx.x;
  const int wave = tid >> 6;
  const int lane = tid & 63;
  const int m0 = blockIdx.y * 128;
  const int n0 = blockIdx.x * 128;
  const int wm = (wave >> 1) * 64;
  const int wn = (wave & 1) * 64;
  const int ln = lane & 15;
  const int kg = lane >> 4;

  __shared__ short lds[8192];  // A tile [128][32] at 0, BT tile at 4096

  f32x4 acc[4][4] = {};

  const int rowA = lane >> 2;       // row within 16-row chunk
  const int colK = (lane & 3) * 8;  // k offset of this lane's 16B

  for (int kt = 0; kt < Keff; kt += 32) {
    __syncthreads();
#pragma unroll
    for (int c2 = 0; c2 < 2; ++c2) {
      const int chunk = c2 * 4 + wave;    // 0..7, 16 rows each
      const int row = chunk * 16 + rowA;  // 0..127
      gld16(A + (size_t)(m0 + row) * 768 + kt + colK, &lds[chunk * 512], lane);
      gld16(BT + (size_t)(n0 + row) * 768 + kt + colK, &lds[4096 + chunk * 512],
            lane);
    }
    __syncthreads();

    bf16x8 af[4], bv[4];
#pragma unroll
    for (int r = 0; r < 4; ++r)
      af[r] = *reinterpret_cast<const bf16x8*>(
          &lds[(wm + r * 16 + ln) * 32 + kg * 8]);
#pragma unroll
    for (int c = 0; c < 4; ++c)
      bv[c] = *reinterpret_cast<const bf16x8*>(
          &lds[4096 + (wn + c * 16 + ln) * 32 + kg * 8]);

#pragma unroll
    for (int r = 0; r < 4; ++r)
#pragma unroll
      for (int c = 0; c < 4; ++c)
        acc[r][c] = __builtin_amdgcn_mfma_f32_16x16x32_bf16(
            af[r], bv[c], acc[r][c], 0, 0, 0);
  }

#pragma unroll
  for (int c = 0; c < 4; ++c) {
    const int nn = n0 + wn + c * 16 + ln;
    const float bvl = bias[nn];
#pragma unroll
    for (int r = 0; r < 4; ++r)
#pragma unroll
      for (int j = 0; j < 4; ++j) {
        const int mm = m0 + wm + r * 16 + kg * 4 + j;
        outp[(size_t)mm * ldc + nn] = acc[r][c][j] + bvl;
      }
  }
}

// -------------------------------------------------------------- transpose ----
// out[c][r] = (bf16) in[r][c]; in fp32 (row stride C), out bf16 (stride
// outStride). 64x64 tiles.
__global__ __launch_bounds__(256) void k_transpose(
    const float* __restrict__ in, unsigned short* __restrict__ out,
    int C, int outStride) {
  __shared__ float t[64][65];
  const int tx = threadIdx.x & 15, ty = threadIdx.x >> 4;
  const int r0 = blockIdx.y * 64, c0 = blockIdx.x * 64;
#pragma unroll
  for (int i = 0; i < 4; ++i) {
    const int r = ty + i * 16;
    const float4 v = *(const float4*)&in[(size_t)(r0 + r) * C + c0 + tx * 4];
    t[r][tx * 4 + 0] = v.x;
    t[r][tx * 4 + 1] = v.y;
    t[r][tx * 4 + 2] = v.z;
    t[r][tx * 4 + 3] = v.w;
  }
  __syncthreads();
#pragma unroll
  for (int i = 0; i < 4; ++i) {
    const int a = ty + i * 16;
    ushort4 v;
    v.x = f2bu(t[tx * 4 + 0][a]);
    v.y = f2bu(t[tx * 4 + 1][a]);
    v.z = f2bu(t[tx * 4 + 2][a]);
    v.w = f2bu(t[tx * 4 + 3][a]);
    *(ushort4*)&out[(size_t)(c0 + a) * outStride + r0 + tx * 4] = v;
  }
}

// ------------------------------------------------------------ small kernels --
__global__ void k_embed(const int* __restrict__ tok,
                        const float* __restrict__ emb,
                        const float* __restrict__ pos, float* __restrict__ x) {
  const int idx = blockIdx.x * 256 + threadIdx.x;  // exactly T*D
  const int t = idx / D, d = idx - t * D;
  const int tk = tok[t];
  x[idx] = emb[(size_t)tk * D + d] + pos[(size_t)(t & (L - 1)) * D + d];
}

__global__ void k_f2b(const float* __restrict__ x, bf16* __restrict__ o) {
  const int idx = blockIdx.x * 256 + threadIdx.x;  // exactly T*D
  o[idx] = f2b(x[idx]);
}

// LayerNorm fp32->fp32. If gw != nullptr also emit fp32 gate logits (+gb).
__global__ __launch_bounds__(256) void k_ln(const float* __restrict__ x,
                                            const float* __restrict__ g,
                                            const float* __restrict__ bb,
                                            float* __restrict__ xn,
                                            const float* __restrict__ gw,
                                            const float* __restrict__ gb,
                                            float* __restrict__ glog) {
  const int row = blockIdx.x, tid = threadIdx.x;
  const float* xr = x + (size_t)row * D;
  const float v0 = xr[tid], v1 = xr[tid + 256], v2 = xr[tid + 512];
  float s = v0 + v1 + v2, s2 = v0 * v0 + v1 * v1 + v2 * v2;
  for (int off = 1; off < 64; off <<= 1) {
    s += __shfl_xor(s, off);
    s2 += __shfl_xor(s2, off);
  }
  __shared__ float rs[4], rs2[4];
  const int w = tid >> 6;
  if ((tid & 63) == 0) { rs[w] = s; rs2[w] = s2; }
  __syncthreads();
  const float S = rs[0] + rs[1] + rs[2] + rs[3];
  const float S2 = rs2[0] + rs2[1] + rs2[2] + rs2[3];
  const float mean = S * (1.f / 768.f);
  const float var = fmaxf(S2 * (1.f / 768.f) - mean * mean, 0.f);
  const float rstd = rsqrtf(var + 1e-5f);
  const float o0 = (v0 - mean) * rstd * g[tid]       + bb[tid];
  const float o1 = (v1 - mean) * rstd * g[tid + 256] + bb[tid + 256];
  const float o2 = (v2 - mean) * rstd * g[tid + 512] + bb[tid + 512];
  float* xo = xn + (size_t)row * D;
  xo[tid] = o0;
  xo[tid + 256] = o1;
  xo[tid + 512] = o2;

  if (gw != nullptr) {
    const float4 ga = *(const float4*)&gw[tid * 4];
    const float4 gbv = *(const float4*)&gw[(tid + 256) * 4];
    const float4 gc = *(const float4*)&gw[(tid + 512) * 4];
    float p0 = o0 * ga.x + o1 * gbv.x + o2 * gc.x;
    float p1 = o0 * ga.y + o1 * gbv.y + o2 * gc.y;
    float p2 = o0 * ga.z + o1 * gbv.z + o2 * gc.z;
    float p3 = o0 * ga.w + o1 * gbv.w + o2 * gc.w;
    for (int off = 1; off < 64; off <<= 1) {
      p0 += __shfl_xor(p0, off);
      p1 += __shfl_xor(p1, off);
      p2 += __shfl_xor(p2, off);
      p3 += __shfl_xor(p3, off);
    }
    __shared__ float rg[4][4];
    if ((tid & 63) == 0) {
      rg[w][0] = p0; rg[w][1] = p1; rg[w][2] = p2; rg[w][3] = p3;
    }
    __syncthreads();
    if (tid == 0) {
      float* gl = glog + (size_t)row * 4;
#pragma unroll
      for (int e = 0; e < 4; ++e)
        gl[e] = rg[0][e] + rg[1][e] + rg[2][e] + rg[3][e] + gb[e];
    }
  }
}

// top-2 + softmax over 4 gate logits -> srow[T][4]
__global__ void k_topk(const float* __restrict__ glog,
                       float* __restrict__ srow) {
  const int t = blockIdx.x * 256 + threadIdx.x;  // exactly T
  float gv[4];
#pragma unroll
  for (int i = 0; i < 4; ++i) gv[i] = glog[t * 4 + i];
  int i1 = 0;
#pragma unroll
  for (int i = 1; i < 4; ++i)
    if (gv[i] > gv[i1]) i1 = i;
  int i2 = -1;
#pragma unroll
  for (int i = 0; i < 4; ++i) {
    if (i == i1) continue;
    if (i2 < 0 || gv[i] > gv[i2]) i2 = i;
  }
  const float e = expf(gv[i2] - gv[i1]);
  const float wa = 1.f / (1.f + e), wb = e / (1.f + e);
  float o[4] = {0.f, 0.f, 0.f, 0.f};
  o[i1] = wa;
  o[i2] = wb;
#pragma unroll
  for (int i = 0; i < 4; ++i) srow[t * 4 + i] = o[i];
}

__global__ void k_cat3(const float* __restrict__ a, const float* __restrict__ b,
                       const float* __restrict__ c, float* __restrict__ o) {
  const int i = blockIdx.x * 256 + threadIdx.x;  // exactly 2304
  o[i] = i < 768 ? a[i] : (i < 1536 ? b[i - 768] : c[i - 1536]);
}

// wqkv[k][j] (768x2304) from qw/kw/vw (each 768x768), fp32
__global__ void k_catW(const float* __restrict__ qw,
                       const float* __restrict__ kw,
                       const float* __restrict__ vw, float* __restrict__ o) {
  const int idx = blockIdx.x * 256 + threadIdx.x;  // exactly 768*2304
  const int k = idx / 2304, j = idx - k * 2304;
  float v;
  if (j < 768) v = qw[k * 768 + j];
  else if (j < 1536) v = kw[k * 768 + (j - 768)];
  else v = vw[k * 768 + (j - 1536)];
  o[idx] = v;
}

// Partial KV/Z over an L-chunk of 128 rows. part[c][bh][e*64+f], Z at +4096.
__global__ __launch_bounds__(256) void k_kvpart(const float* __restrict__ qkv,
                                                float* __restrict__ part) {
  const int bh = blockIdx.x;  // 0..23
  const int b = bh / NH, h = bh % NH;
  const int c = blockIdx.y;  // 0..7
  const int tid = threadIdx.x;
  __shared__ float kf[64], vv[64];
  float acc[16];
#pragma unroll
  for (int j = 0; j < 16; ++j) acc[j] = 0.f;
  float zacc = 0.f;
  const int e = tid >> 2;
  const int f0 = (tid & 3) * 16;
  const int t0 = b * L + c * 128;
  for (int i = 0; i < 128; ++i) {
    __syncthreads();
    const size_t rowb = (size_t)(t0 + i) * 2304;
    if (tid < 64) kf[tid] = qkv[rowb + 768 + h * 64 + tid];
    else if (tid < 128) vv[tid - 64] = qkv[rowb + 1536 + h * 64 + (tid - 64)];
    __syncthreads();
    const float ke = kf[e];
#pragma unroll
    for (int j = 0; j < 16; ++j) acc[j] += ke * vv[f0 + j];
    if (tid < 64) zacc += kf[tid];
  }
  const size_t base = ((size_t)c * 24 + bh) * 4160;
#pragma unroll
  for (int j = 0; j < 16; ++j) part[base + e * 64 + f0 + j] = acc[j];
  if (tid < 64) part[base + 4096 + tid] = zacc;
}

__global__ void k_kvred(const float* __restrict__ part, float* __restrict__ kv) {
  const int idx = blockIdx.x * 256 + threadIdx.x;  // exactly 24*4160
  float s = 0.f;
#pragma unroll
  for (int cc = 0; cc < 8; ++cc) s += part[(size_t)cc * 99840 + idx];
  kv[idx] = s;
}

__global__ __launch_bounds__(256) void k_attnout(const float* __restrict__ qkv,
                                                 const float* __restrict__ kv,
                                                 float* __restrict__ att) {
  const int t = blockIdx.x;
  const int b = t >> 10;
  const int tid = threadIdx.x;
  __shared__ float q[768];
  __shared__ float den[12];
  for (int i = tid; i < 768; i += 256) q[i] = qkv[(size_t)t * 2304 + i];
  __syncthreads();
  if (tid < 12) {
    const float* zz = kv + ((size_t)(b * NH + tid)) * 4160 + 4096;
    float s = 0.f;
#pragma unroll
    for (int e = 0; e < 64; ++e) s += q[tid * 64 + e] * zz[e];
    den[tid] = s + 1e-6f;
  }
  __syncthreads();
  for (int i = tid; i < 768; i += 256) {
    const int h = i >> 6, f = i & 63;
    const float* Kv = kv + ((size_t)(b * NH + h)) * 4160;
    float s = 0.f;
#pragma unroll
    for (int e = 0; e < 64; ++e) s += q[h * 64 + e] * Kv[e * 64 + f];
    att[(size_t)t * 768 + i] = s / den[h];
  }
}

// x += sum_e srow[t][e] * b2[e][n]
__global__ void k_moebias(float* __restrict__ x, const float* __restrict__ srow,
                          const float* __restrict__ b2l) {
  const int idx = blockIdx.x * 256 + threadIdx.x;  // exactly T*D
  const int t = idx / D, n = idx - t * D;
  const float* s = srow + t * 4;
  x[idx] += s[0] * b2l[n] + s[1] * b2l[D + n] + s[2] * b2l[2 * D + n] +
            s[3] * b2l[3 * D + n];
}

// ------------------------------------------------------------------ launch ---
extern "C" void kernel_launch(void* const* d_in, const int* in_sizes, int n_in,
                              void* d_out, int out_size, void* d_ws,
                              size_t ws_size, hipStream_t stream) {
  const int*   tokens = (const int*)d_in[0];
  const float* emb  = (const float*)d_in[1];
  const float* pos  = (const float*)d_in[2];
  const float* qw   = (const float*)d_in[3];
  const float* qb   = (const float*)d_in[4];
  const float* kw   = (const float*)d_in[5];
  const float* kb   = (const float*)d_in[6];
  const float* vw   = (const float*)d_in[7];
  const float* vb   = (const float*)d_in[8];
  const float* ow   = (const float*)d_in[9];
  const float* ob   = (const float*)d_in[10];
  const float* ln1g = (const float*)d_in[11];
  const float* ln1b = (const float*)d_in[12];
  const float* ln2g = (const float*)d_in[13];
  const float* ln2b = (const float*)d_in[14];
  const float* gw   = (const float*)d_in[15];
  const float* gb   = (const float*)d_in[16];
  const float* w1   = (const float*)d_in[17];
  const float* b1   = (const float*)d_in[18];
  const float* w2   = (const float*)d_in[19];
  const float* b2   = (const float*)d_in[20];
  const float* hw   = (const float*)d_in[21];
  const float* hb   = (const float*)d_in[22];

  char* p = (char*)d_ws;
  auto alloc = [&](size_t bytes) -> void* {
    void* r = (void*)p;
    p += (bytes + 255) & ~((size_t)255);
    return r;
  };
  float* x    = (float*)alloc((size_t)T * D * 4);          // 6.3 MB
  float* xn   = (float*)alloc((size_t)T * D * 4);          // 6.3 MB
  float* qkvb = (float*)alloc((size_t)T * 2304 * 4);       // 18.9 MB
  float* att  = (float*)alloc((size_t)T * D * 4);          // 6.3 MB
  float* kvp  = (float*)alloc((size_t)8 * 24 * 4160 * 4);  // 3.2 MB
  float* kv   = (float*)alloc((size_t)24 * 4160 * 4);      // 0.4 MB
  float* srow = (float*)alloc((size_t)T * 4 * 4);
  float* glog = (float*)alloc((size_t)T * 4 * 4);
  float* bqkv = (float*)alloc((size_t)2304 * 4);
  float* wqkv = (float*)alloc((size_t)D * 2304 * 4);       // 7.1 MB
  // hs [T][12288] fp32 = 100.7 MB lives in d_out (262 MB), overwritten by the
  // final head GEMM afterwards.
  float* hs = (float*)d_out;
  // Head-phase overlays (regions dead by then): xb on xn; hwT half-panel
  // (16000x768 bf16 = 24.6 MB) on qkvb+att (25.2 MB contiguous).
  bf16* xb  = (bf16*)xn;
  bf16* hwT = (bf16*)qkvb;

  k_embed<<<dim3(6144), 256, 0, stream>>>(tokens, emb, pos, x);

  for (int l = 0; l < NL; ++l) {
    const size_t DD = (size_t)D * D;
    k_catW<<<dim3(6912), 256, 0, stream>>>(qw + l * DD, kw + l * DD,
                                           vw + l * DD, wqkv);
    k_cat3<<<dim3(9), 256, 0, stream>>>(qb + l * D, kb + l * D, vb + l * D,
                                        bqkv);

    // attention
    k_ln<<<dim3(T), 256, 0, stream>>>(x, ln1g + l * D, ln1b + l * D, xn,
                                      nullptr, nullptr, nullptr);
    k_fgemm<1><<<dim3(18, 16, 1), 256, 0, stream>>>(
        xn, D, 0, wqkv, 2304, 0, bqkv, 0, qkvb, 2304, 0, nullptr, 2304, D);
    k_kvpart<<<dim3(24, 8), 256, 0, stream>>>(qkvb, kvp);
    k_kvred<<<dim3(390), 256, 0, stream>>>(kvp, kv);
    k_attnout<<<dim3(T), 256, 0, stream>>>(qkvb, kv, att);
    k_fgemm<2><<<dim3(6, 16, 1), 256, 0, stream>>>(
        att, D, 0, ow + l * DD, D, 0, ob + l * D, 0, x, D, 0, nullptr, D, D);

    // MoE
    k_ln<<<dim3(T), 256, 0, stream>>>(x, ln2g + l * D, ln2b + l * D, xn,
                                      gw + (size_t)l * D * NE, gb + l * NE,
                                      glog);
    k_topk<<<dim3(8), 256, 0, stream>>>(glog, srow);
    k_fgemm<3><<<dim3(24, 16, 4), 256, 0, stream>>>(
        xn, D, 0, w1 + (size_t)l * NE * D * DH, DH, (long)D * DH,
        b1 + (size_t)l * NE * DH, DH, hs, 12288, DH, srow, DH, D);
    k_moebias<<<dim3(6144), 256, 0, stream>>>(x, srow,
                                              b2 + (size_t)l * NE * D);
    k_fgemm<4><<<dim3(6, 16, 4), 256, 0, stream>>>(
        hs, 12288, 3072, w2 + (size_t)l * NE * DH * D, D, (long)DH * D,
        nullptr, 0, x, D, 0, nullptr, D, DH);
  }

  // ------------------------------------------------------------- head -------
  // d_out = x @ hw + hb via bf16 MFMA in two N=16000 halves (hs dead now;
  // hwT/xb overlays live in dead ws regions).
  k_f2b<<<dim3(6144), 256, 0, stream>>>(x, xb);
  for (int half = 0; half < 2; ++half) {
    k_transpose<<<dim3(250, 12, 1), 256, 0, stream>>>(
        hw + half * 16000, (unsigned short*)hwT, V, D);
    k_bgemm<<<dim3(125, 16, 1), 256, 0, stream>>>(
        xb, hwT, hb + half * 16000, (float*)d_out + half * 16000, V, D);
  }
}

// Round 9
// 5252.529 us; speedup vs baseline: 2.5226x; 1.3090x over previous
//
#include <hip/hip_runtime.h>
#include <hip/hip_bf16.h>
#include <cstdint>
#include <cstddef>

typedef __hip_bfloat16 bf16;
typedef __attribute__((ext_vector_type(8))) short bf16x8;
typedef __attribute__((ext_vector_type(4))) float f32x4;

#define DEV __device__ __forceinline__

static constexpr int D  = 768;
static constexpr int NH = 12;
static constexpr int NE = 4;
static constexpr int DH = 3072;
static constexpr int L  = 1024;
static constexpr int T  = 2048;
static constexpr int V  = 32000;
static constexpr int NL = 4;

DEV bf16 f2b(float f) { return __float2bfloat16(f); }
DEV unsigned short f2bu(float f) {
  bf16 b = f2b(f);
  return *reinterpret_cast<unsigned short*>(&b);
}
DEV float gelu(float v) {
  return 0.5f * v * (1.f + erff(v * 0.70710678118654752f));
}

// ---------------------------------------------------------------- staging ----
DEV void gld16(const void* g, short* ldsbase, int lane) {
#if __has_builtin(__builtin_amdgcn_global_load_lds)
  (void)lane;
  __builtin_amdgcn_global_load_lds(
      (const __attribute__((address_space(1))) unsigned int*)g,
      (__attribute__((address_space(3))) unsigned int*)ldsbase, 16, 0, 0);
#else
  *reinterpret_cast<bf16x8*>(ldsbase + lane * 8) =
      *reinterpret_cast<const bf16x8*>(g);
#endif
}

// ------------------------------------------------------------- fp32 GEMM ----
// r5-proven structure: single-buffer LDS, BK=16, 128x128 tile, 8x8 microtile.
// r9: COMP reads use 4+4 split (cols tx*4 and 64+tx*4) -> 2-way LDS access
// (free) instead of 4-way. Staging and global traffic identical to r5.
// EPI: 1 = qkv (elu+1 for col<1536); 2 = out += acc+bias.
template <int EPI>
__global__ __launch_bounds__(256) void k_fgemm(
    const float* __restrict__ A, int lda,
    const float* __restrict__ B, int ldb,
    const float* __restrict__ bias,
    float* __restrict__ outp, int ldc,
    int Keff) {
  const int tid = threadIdx.x;
  const int tx = tid & 15;
  const int ty = tid >> 4;
  const int m0 = blockIdx.y * 128;
  const int n0 = blockIdx.x * 128;

  __shared__ float As[16 * 132];  // [kk][m]
  __shared__ float Bs[16 * 132];  // [kk][n]

  float acc[8][8];
#pragma unroll
  for (int i = 0; i < 8; ++i)
#pragma unroll
    for (int j = 0; j < 8; ++j) acc[i][j] = 0.f;

  const int sk = tid & 15;
  const int sm = tid >> 4;

  for (int kt = 0; kt < Keff; kt += 16) {
    __syncthreads();
#pragma unroll
    for (int i = 0; i < 8; ++i) {
      const int m = sm + 16 * i;
      As[sk * 132 + m] = A[(size_t)(m0 + m) * lda + kt + sk];
    }
#pragma unroll
    for (int i = 0; i < 8; ++i) {
      const int idx = tid + 256 * i;
      const int kk = idx >> 7, n = idx & 127;
      Bs[kk * 132 + n] = B[(size_t)(kt + kk) * ldb + n0 + n];
    }
    __syncthreads();

#pragma unroll
    for (int kk = 0; kk < 16; ++kk) {
      const float4 aLo = *(const float4*)&As[kk * 132 + ty * 4];
      const float4 aHi = *(const float4*)&As[kk * 132 + 64 + ty * 4];
      const float4 bLo = *(const float4*)&Bs[kk * 132 + tx * 4];
      const float4 bHi = *(const float4*)&Bs[kk * 132 + 64 + tx * 4];
      const float av[8] = {aLo.x, aLo.y, aLo.z, aLo.w,
                           aHi.x, aHi.y, aHi.z, aHi.w};
      const float bv[8] = {bLo.x, bLo.y, bLo.z, bLo.w,
                           bHi.x, bHi.y, bHi.z, bHi.w};
#pragma unroll
      for (int i = 0; i < 8; ++i)
#pragma unroll
        for (int j = 0; j < 8; ++j) acc[i][j] += av[i] * bv[j];
    }
  }

#pragma unroll
  for (int jh = 0; jh < 2; ++jh)
#pragma unroll
    for (int j = 0; j < 4; ++j) {
      const int col = n0 + jh * 64 + tx * 4 + j;
      const float bvl = bias[col];
#pragma unroll
      for (int ih = 0; ih < 2; ++ih)
#pragma unroll
        for (int i = 0; i < 4; ++i) {
          const int mm = m0 + ih * 64 + ty * 4 + i;
          const float v = acc[ih * 4 + i][jh * 4 + j] + bvl;
          const size_t idx = (size_t)mm * ldc + col;
          if constexpr (EPI == 1) {
            outp[idx] = (col < 1536) ? (v > 0.f ? v + 1.f : expf(v)) : v;
          } else {
            outp[idx] += v;
          }
        }
    }
}

// ------------------------------------------------------- sparse MoE GEMMs ---
// PH=0 (UP):   hse[z][pos][3072] = gelu(xn[list[z][pos]] @ w1[z] + b1[z])
//              * srow[tok][z]          (rows gathered via list)
// PH=1 (DOWN): xc[rank][tok][768] = hse[z][pos] @ w2[z]   (pos < cnt[z])
// Both: 128x128 tile, BK=16, 4+4-split COMP, early-exit when m0 >= cnt[z].
template <int PH>
__global__ __launch_bounds__(256) void k_mgemm(
    const float* __restrict__ A, const float* __restrict__ B,
    const float* __restrict__ bias, float* __restrict__ outp,
    const float* __restrict__ srow, const int* __restrict__ list,
    const int* __restrict__ rnkl, const int* __restrict__ cnt) {
  const int z = blockIdx.z;
  const int m0 = blockIdx.y * 128;
  const int cz = cnt[z];
  if (m0 >= cz) return;
  const int n0 = blockIdx.x * 128;
  constexpr int K   = PH == 0 ? 768 : 3072;
  constexpr int LDA = PH == 0 ? 768 : 3072;
  constexpr int LDB = PH == 0 ? 3072 : 768;
  const float* Bz = B + (size_t)z * K * (PH == 0 ? 3072 : 768);

  const int tid = threadIdx.x;
  const int tx = tid & 15;
  const int ty = tid >> 4;

  __shared__ float As[16 * 132];
  __shared__ float Bs[16 * 132];
  __shared__ int rows[128];
  __shared__ int rnks[128];
  if (tid < 128) {
    rows[tid] = list[z * 2048 + m0 + tid];  // padded -> always valid token
    if (PH == 1) rnks[tid] = rnkl[z * 2048 + m0 + tid];
  }

  float acc[8][8];
#pragma unroll
  for (int i = 0; i < 8; ++i)
#pragma unroll
    for (int j = 0; j < 8; ++j) acc[i][j] = 0.f;

  const int sk = tid & 15;
  const int sm = tid >> 4;

  for (int kt = 0; kt < K; kt += 16) {
    __syncthreads();
#pragma unroll
    for (int i = 0; i < 8; ++i) {
      const int m = sm + 16 * i;
      const int arow = (PH == 0) ? rows[m] : (z * 2048 + m0 + m);
      As[sk * 132 + m] = A[(size_t)arow * LDA + kt + sk];
    }
#pragma unroll
    for (int i = 0; i < 8; ++i) {
      const int idx = tid + 256 * i;
      const int kk = idx >> 7, n = idx & 127;
      Bs[kk * 132 + n] = Bz[(size_t)(kt + kk) * LDB + n0 + n];
    }
    __syncthreads();

#pragma unroll
    for (int kk = 0; kk < 16; ++kk) {
      const float4 aLo = *(const float4*)&As[kk * 132 + ty * 4];
      const float4 aHi = *(const float4*)&As[kk * 132 + 64 + ty * 4];
      const float4 bLo = *(const float4*)&Bs[kk * 132 + tx * 4];
      const float4 bHi = *(const float4*)&Bs[kk * 132 + 64 + tx * 4];
      const float av[8] = {aLo.x, aLo.y, aLo.z, aLo.w,
                           aHi.x, aHi.y, aHi.z, aHi.w};
      const float bv[8] = {bLo.x, bLo.y, bLo.z, bLo.w,
                           bHi.x, bHi.y, bHi.z, bHi.w};
#pragma unroll
      for (int i = 0; i < 8; ++i)
#pragma unroll
        for (int j = 0; j < 8; ++j) acc[i][j] += av[i] * bv[j];
    }
  }

#pragma unroll
  for (int ih = 0; ih < 2; ++ih)
#pragma unroll
    for (int i = 0; i < 4; ++i) {
      const int ml = ih * 64 + ty * 4 + i;  // local row in tile
      if constexpr (PH == 0) {
        const int pos = m0 + ml;
        const int tok = rows[ml];
        const float s = srow[tok * 4 + z];
        float* op = outp + ((size_t)z * 2048 + pos) * 3072;
#pragma unroll
        for (int jh = 0; jh < 2; ++jh)
#pragma unroll
          for (int j = 0; j < 4; ++j) {
            const int col = n0 + jh * 64 + tx * 4 + j;
            const float v = acc[ih * 4 + i][jh * 4 + j] + bias[z * 3072 + col];
            op[col] = s * gelu(v);
          }
      } else {
        if (m0 + ml < cz) {
          const int tok = rows[ml];
          const int rk = rnks[ml];
          float* op = outp + ((size_t)rk * T + tok) * 768;
#pragma unroll
          for (int jh = 0; jh < 2; ++jh)
#pragma unroll
            for (int j = 0; j < 4; ++j) {
              const int col = n0 + jh * 64 + tx * 4 + j;
              op[col] = acc[ih * 4 + i][jh * 4 + j];
            }
        }
      }
    }
}

// ----------------------------------------------------- bf16 MFMA head GEMM --
__global__ __launch_bounds__(256) void k_bgemm(
    const bf16* __restrict__ A, const bf16* __restrict__ BT,
    const float* __restrict__ bias, float* __restrict__ outp,
    int ldc, int Keff) {
  const int tid  = threadIdx.x;
  const int wave = tid >> 6;
  const int lane = tid & 63;
  const int m0 = blockIdx.y * 128;
  const int n0 = blockIdx.x * 128;
  const int wm = (wave >> 1) * 64;
  const int wn = (wave & 1) * 64;
  const int ln = lane & 15;
  const int kg = lane >> 4;

  __shared__ short lds[8192];

  f32x4 acc[4][4] = {};

  const int rowA = lane >> 2;
  const int colK = (lane & 3) * 8;

  for (int kt = 0; kt < Keff; kt += 32) {
    __syncthreads();
#pragma unroll
    for (int c2 = 0; c2 < 2; ++c2) {
      const int chunk = c2 * 4 + wave;
      const int row = chunk * 16 + rowA;
      gld16(A + (size_t)(m0 + row) * 768 + kt + colK, &lds[chunk * 512], lane);
      gld16(BT + (size_t)(n0 + row) * 768 + kt + colK, &lds[4096 + chunk * 512],
            lane);
    }
    __syncthreads();

    bf16x8 af[4], bv[4];
#pragma unroll
    for (int r = 0; r < 4; ++r)
      af[r] = *reinterpret_cast<const bf16x8*>(
          &lds[(wm + r * 16 + ln) * 32 + kg * 8]);
#pragma unroll
    for (int c = 0; c < 4; ++c)
      bv[c] = *reinterpret_cast<const bf16x8*>(
          &lds[4096 + (wn + c * 16 + ln) * 32 + kg * 8]);

#pragma unroll
    for (int r = 0; r < 4; ++r)
#pragma unroll
      for (int c = 0; c < 4; ++c)
        acc[r][c] = __builtin_amdgcn_mfma_f32_16x16x32_bf16(
            af[r], bv[c], acc[r][c], 0, 0, 0);
  }

#pragma unroll
  for (int c = 0; c < 4; ++c) {
    const int nn = n0 + wn + c * 16 + ln;
    const float bvl = bias[nn];
#pragma unroll
    for (int r = 0; r < 4; ++r)
#pragma unroll
      for (int j = 0; j < 4; ++j) {
        const int mm = m0 + wm + r * 16 + kg * 4 + j;
        outp[(size_t)mm * ldc + nn] = acc[r][c][j] + bvl;
      }
  }
}

// -------------------------------------------------------------- transpose ----
__global__ __launch_bounds__(256) void k_transpose(
    const float* __restrict__ in, unsigned short* __restrict__ out,
    int C, int outStride) {
  __shared__ float t[64][65];
  const int tx = threadIdx.x & 15, ty = threadIdx.x >> 4;
  const int r0 = blockIdx.y * 64, c0 = blockIdx.x * 64;
#pragma unroll
  for (int i = 0; i < 4; ++i) {
    const int r = ty + i * 16;
    const float4 v = *(const float4*)&in[(size_t)(r0 + r) * C + c0 + tx * 4];
    t[r][tx * 4 + 0] = v.x;
    t[r][tx * 4 + 1] = v.y;
    t[r][tx * 4 + 2] = v.z;
    t[r][tx * 4 + 3] = v.w;
  }
  __syncthreads();
#pragma unroll
  for (int i = 0; i < 4; ++i) {
    const int a = ty + i * 16;
    ushort4 v;
    v.x = f2bu(t[tx * 4 + 0][a]);
    v.y = f2bu(t[tx * 4 + 1][a]);
    v.z = f2bu(t[tx * 4 + 2][a]);
    v.w = f2bu(t[tx * 4 + 3][a]);
    *(ushort4*)&out[(size_t)(c0 + a) * outStride + r0 + tx * 4] = v;
  }
}

// ------------------------------------------------------------ small kernels --
__global__ void k_embed(const int* __restrict__ tok,
                        const float* __restrict__ emb,
                        const float* __restrict__ pos, float* __restrict__ x) {
  const int idx = blockIdx.x * 256 + threadIdx.x;
  const int t = idx / D, d = idx - t * D;
  const int tk = tok[t];
  x[idx] = emb[(size_t)tk * D + d] + pos[(size_t)(t & (L - 1)) * D + d];
}

__global__ void k_f2b(const float* __restrict__ x, bf16* __restrict__ o) {
  const int idx = blockIdx.x * 256 + threadIdx.x;
  o[idx] = f2b(x[idx]);
}

// LayerNorm fp32->fp32. If gw != nullptr also emit fp32 gate logits (+gb).
__global__ __launch_bounds__(256) void k_ln(const float* __restrict__ x,
                                            const float* __restrict__ g,
                                            const float* __restrict__ bb,
                                            float* __restrict__ xn,
                                            const float* __restrict__ gw,
                                            const float* __restrict__ gb,
                                            float* __restrict__ glog) {
  const int row = blockIdx.x, tid = threadIdx.x;
  const float* xr = x + (size_t)row * D;
  const float v0 = xr[tid], v1 = xr[tid + 256], v2 = xr[tid + 512];
  float s = v0 + v1 + v2, s2 = v0 * v0 + v1 * v1 + v2 * v2;
  for (int off = 1; off < 64; off <<= 1) {
    s += __shfl_xor(s, off);
    s2 += __shfl_xor(s2, off);
  }
  __shared__ float rs[4], rs2[4];
  const int w = tid >> 6;
  if ((tid & 63) == 0) { rs[w] = s; rs2[w] = s2; }
  __syncthreads();
  const float S = rs[0] + rs[1] + rs[2] + rs[3];
  const float S2 = rs2[0] + rs2[1] + rs2[2] + rs2[3];
  const float mean = S * (1.f / 768.f);
  const float var = fmaxf(S2 * (1.f / 768.f) - mean * mean, 0.f);
  const float rstd = rsqrtf(var + 1e-5f);
  const float o0 = (v0 - mean) * rstd * g[tid]       + bb[tid];
  const float o1 = (v1 - mean) * rstd * g[tid + 256] + bb[tid + 256];
  const float o2 = (v2 - mean) * rstd * g[tid + 512] + bb[tid + 512];
  float* xo = xn + (size_t)row * D;
  xo[tid] = o0;
  xo[tid + 256] = o1;
  xo[tid + 512] = o2;

  if (gw != nullptr) {
    const float4 ga = *(const float4*)&gw[tid * 4];
    const float4 gbv = *(const float4*)&gw[(tid + 256) * 4];
    const float4 gc = *(const float4*)&gw[(tid + 512) * 4];
    float p0 = o0 * ga.x + o1 * gbv.x + o2 * gc.x;
    float p1 = o0 * ga.y + o1 * gbv.y + o2 * gc.y;
    float p2 = o0 * ga.z + o1 * gbv.z + o2 * gc.z;
    float p3 = o0 * ga.w + o1 * gbv.w + o2 * gc.w;
    for (int off = 1; off < 64; off <<= 1) {
      p0 += __shfl_xor(p0, off);
      p1 += __shfl_xor(p1, off);
      p2 += __shfl_xor(p2, off);
      p3 += __shfl_xor(p3, off);
    }
    __shared__ float rg[4][4];
    if ((tid & 63) == 0) {
      rg[w][0] = p0; rg[w][1] = p1; rg[w][2] = p2; rg[w][3] = p3;
    }
    __syncthreads();
    if (tid == 0) {
      float* gl = glog + (size_t)row * 4;
#pragma unroll
      for (int e = 0; e < 4; ++e)
        gl[e] = rg[0][e] + rg[1][e] + rg[2][e] + rg[3][e] + gb[e];
    }
  }
}

// top-2 softmax weights + deterministic per-expert token lists.
// 1 block, 256 threads (4 waves; wave w owns expert w's list).
__global__ __launch_bounds__(256) void k_scan(const float* __restrict__ glog,
                                              float* __restrict__ srow,
                                              int* __restrict__ list,
                                              int* __restrict__ rnkl,
                                              int* __restrict__ cnt) {
  const int tid = threadIdx.x;
  __shared__ unsigned char e1s[2048], e2s[2048];
  for (int t = tid; t < T; t += 256) {
    float gv[4];
#pragma unroll
    for (int i = 0; i < 4; ++i) gv[i] = glog[t * 4 + i];
    int i1 = 0;
#pragma unroll
    for (int i = 1; i < 4; ++i)
      if (gv[i] > gv[i1]) i1 = i;
    int i2 = -1;
#pragma unroll
    for (int i = 0; i < 4; ++i) {
      if (i == i1) continue;
      if (i2 < 0 || gv[i] > gv[i2]) i2 = i;
    }
    const float e = expf(gv[i2] - gv[i1]);
    const float wa = 1.f / (1.f + e), wb = e / (1.f + e);
    float o[4] = {0.f, 0.f, 0.f, 0.f};
    o[i1] = wa;
    o[i2] = wb;
#pragma unroll
    for (int i = 0; i < 4; ++i) srow[t * 4 + i] = o[i];
    e1s[t] = (unsigned char)i1;
    e2s[t] = (unsigned char)i2;
  }
  __syncthreads();
  const int w = tid >> 6, lane = tid & 63;
  int base = 0;
  for (int c = 0; c < 32; ++c) {
    const int t = c * 64 + lane;
    const bool f1 = (e1s[t] == w);
    const bool f2 = (e2s[t] == w);
    const bool f = f1 || f2;
    const unsigned long long mask = __ballot(f);
    const int mypos = __popcll(mask & ((1ull << lane) - 1ull));
    if (f) {
      list[w * 2048 + base + mypos] = t;
      rnkl[w * 2048 + base + mypos] = f1 ? 0 : 1;
    }
    base += __popcll(mask);
  }
  if (lane == 0) cnt[w] = base;
  for (int ppos = base + lane; ppos < 2048; ppos += 64) {
    list[w * 2048 + ppos] = 0;
    rnkl[w * 2048 + ppos] = 0;
  }
}

// x += xc[0] + xc[1] + sum_e srow[t][e] * b2[e][n]   (fixed order, no atomics)
__global__ void k_moeadd(float* __restrict__ x, const float* __restrict__ xc,
                         const float* __restrict__ srow,
                         const float* __restrict__ b2l) {
  const int idx = blockIdx.x * 256 + threadIdx.x;  // exactly T*D
  const int t = idx / D, n = idx - t * D;
  const float* s = srow + t * 4;
  x[idx] += xc[idx] + xc[(size_t)T * D + idx] + s[0] * b2l[n] +
            s[1] * b2l[D + n] + s[2] * b2l[2 * D + n] + s[3] * b2l[3 * D + n];
}

__global__ void k_cat3(const float* __restrict__ a, const float* __restrict__ b,
                       const float* __restrict__ c, float* __restrict__ o) {
  const int i = blockIdx.x * 256 + threadIdx.x;
  o[i] = i < 768 ? a[i] : (i < 1536 ? b[i - 768] : c[i - 1536]);
}

__global__ void k_catW(const float* __restrict__ qw,
                       const float* __restrict__ kw,
                       const float* __restrict__ vw, float* __restrict__ o) {
  const int idx = blockIdx.x * 256 + threadIdx.x;
  const int k = idx / 2304, j = idx - k * 2304;
  float v;
  if (j < 768) v = qw[k * 768 + j];
  else if (j < 1536) v = kw[k * 768 + (j - 768)];
  else v = vw[k * 768 + (j - 1536)];
  o[idx] = v;
}

// Partial KV/Z over an L-chunk of 128 rows. part[c][bh][e*64+f], Z at +4096.
__global__ __launch_bounds__(256) void k_kvpart(const float* __restrict__ qkv,
                                                float* __restrict__ part) {
  const int bh = blockIdx.x;
  const int b = bh / NH, h = bh % NH;
  const int c = blockIdx.y;
  const int tid = threadIdx.x;
  __shared__ float kf[64], vv[64];
  float acc[16];
#pragma unroll
  for (int j = 0; j < 16; ++j) acc[j] = 0.f;
  float zacc = 0.f;
  const int e = tid >> 2;
  const int f0 = (tid & 3) * 16;
  const int t0 = b * L + c * 128;
  for (int i = 0; i < 128; ++i) {
    __syncthreads();
    const size_t rowb = (size_t)(t0 + i) * 2304;
    if (tid < 64) kf[tid] = qkv[rowb + 768 + h * 64 + tid];
    else if (tid < 128) vv[tid - 64] = qkv[rowb + 1536 + h * 64 + (tid - 64)];
    __syncthreads();
    const float ke = kf[e];
#pragma unroll
    for (int j = 0; j < 16; ++j) acc[j] += ke * vv[f0 + j];
    if (tid < 64) zacc += kf[tid];
  }
  const size_t base = ((size_t)c * 24 + bh) * 4160;
#pragma unroll
  for (int j = 0; j < 16; ++j) part[base + e * 64 + f0 + j] = acc[j];
  if (tid < 64) part[base + 4096 + tid] = zacc;
}

__global__ void k_kvred(const float* __restrict__ part, float* __restrict__ kv) {
  const int idx = blockIdx.x * 256 + threadIdx.x;
  float s = 0.f;
#pragma unroll
  for (int cc = 0; cc < 8; ++cc) s += part[(size_t)cc * 99840 + idx];
  kv[idx] = s;
}

__global__ __launch_bounds__(256) void k_attnout(const float* __restrict__ qkv,
                                                 const float* __restrict__ kv,
                                                 float* __restrict__ att) {
  const int t = blockIdx.x;
  const int b = t >> 10;
  const int tid = threadIdx.x;
  __shared__ float q[768];
  __shared__ float den[12];
  for (int i = tid; i < 768; i += 256) q[i] = qkv[(size_t)t * 2304 + i];
  __syncthreads();
  if (tid < 12) {
    const float* zz = kv + ((size_t)(b * NH + tid)) * 4160 + 4096;
    float s = 0.f;
#pragma unroll
    for (int e = 0; e < 64; ++e) s += q[tid * 64 + e] * zz[e];
    den[tid] = s + 1e-6f;
  }
  __syncthreads();
  for (int i = tid; i < 768; i += 256) {
    const int h = i >> 6, f = i & 63;
    const float* Kv = kv + ((size_t)(b * NH + h)) * 4160;
    float s = 0.f;
#pragma unroll
    for (int e = 0; e < 64; ++e) s += q[h * 64 + e] * Kv[e * 64 + f];
    att[(size_t)t * 768 + i] = s / den[h];
  }
}

// ------------------------------------------------------------------ launch ---
extern "C" void kernel_launch(void* const* d_in, const int* in_sizes, int n_in,
                              void* d_out, int out_size, void* d_ws,
                              size_t ws_size, hipStream_t stream) {
  const int*   tokens = (const int*)d_in[0];
  const float* emb  = (const float*)d_in[1];
  const float* pos  = (const float*)d_in[2];
  const float* qw   = (const float*)d_in[3];
  const float* qb   = (const float*)d_in[4];
  const float* kw   = (const float*)d_in[5];
  const float* kb   = (const float*)d_in[6];
  const float* vw   = (const float*)d_in[7];
  const float* vb   = (const float*)d_in[8];
  const float* ow   = (const float*)d_in[9];
  const float* ob   = (const float*)d_in[10];
  const float* ln1g = (const float*)d_in[11];
  const float* ln1b = (const float*)d_in[12];
  const float* ln2g = (const float*)d_in[13];
  const float* ln2b = (const float*)d_in[14];
  const float* gw   = (const float*)d_in[15];
  const float* gb   = (const float*)d_in[16];
  const float* w1   = (const float*)d_in[17];
  const float* b1   = (const float*)d_in[18];
  const float* w2   = (const float*)d_in[19];
  const float* b2   = (const float*)d_in[20];
  const float* hw   = (const float*)d_in[21];
  const float* hb   = (const float*)d_in[22];

  char* p = (char*)d_ws;
  auto alloc = [&](size_t bytes) -> void* {
    void* r = (void*)p;
    p += (bytes + 255) & ~((size_t)255);
    return r;
  };
  float* x    = (float*)alloc((size_t)T * D * 4);
  float* xn   = (float*)alloc((size_t)T * D * 4);
  float* qkvb = (float*)alloc((size_t)T * 2304 * 4);
  float* att  = (float*)alloc((size_t)T * D * 4);
  float* kvp  = (float*)alloc((size_t)8 * 24 * 4160 * 4);
  float* kv   = (float*)alloc((size_t)24 * 4160 * 4);
  float* srow = (float*)alloc((size_t)T * 4 * 4);
  float* glog = (float*)alloc((size_t)T * 4 * 4);
  float* bqkv = (float*)alloc((size_t)2304 * 4);
  float* wqkv = (float*)alloc((size_t)D * 2304 * 4);
  int*   list = (int*)alloc((size_t)NE * 2048 * 4);
  int*   rnkl = (int*)alloc((size_t)NE * 2048 * 4);
  int*   cnt  = (int*)alloc((size_t)16);
  // d_out (262 MB) scratch overlays, dead before the head writes it:
  //   hse [4][2048][3072] fp32 = 100.7 MB at offset 0
  //   xc  [2][T][768] fp32 = 12.6 MB after hse
  float* hse = (float*)d_out;
  float* xc  = hse + (size_t)4 * 2048 * 3072;
  // Head-phase overlays in ws (dead regions): xb on xn; hwT on qkvb+att.
  bf16* xb  = (bf16*)xn;
  bf16* hwT = (bf16*)qkvb;

  k_embed<<<dim3(6144), 256, 0, stream>>>(tokens, emb, pos, x);

  for (int l = 0; l < NL; ++l) {
    const size_t DD = (size_t)D * D;
    k_catW<<<dim3(6912), 256, 0, stream>>>(qw + l * DD, kw + l * DD,
                                           vw + l * DD, wqkv);
    k_cat3<<<dim3(9), 256, 0, stream>>>(qb + l * D, kb + l * D, vb + l * D,
                                        bqkv);

    // attention
    k_ln<<<dim3(T), 256, 0, stream>>>(x, ln1g + l * D, ln1b + l * D, xn,
                                      nullptr, nullptr, nullptr);
    k_fgemm<1><<<dim3(18, 16, 1), 256, 0, stream>>>(
        xn, D, wqkv, 2304, bqkv, qkvb, 2304, D);
    k_kvpart<<<dim3(24, 8), 256, 0, stream>>>(qkvb, kvp);
    k_kvred<<<dim3(390), 256, 0, stream>>>(kvp, kv);
    k_attnout<<<dim3(T), 256, 0, stream>>>(qkvb, kv, att);
    k_fgemm<2><<<dim3(6, 16, 1), 256, 0, stream>>>(
        att, D, ow + l * DD, D, ob + l * D, x, D, D);

    // MoE (sparse top-2, exact fp32)
    k_ln<<<dim3(T), 256, 0, stream>>>(x, ln2g + l * D, ln2b + l * D, xn,
                                      gw + (size_t)l * D * NE, gb + l * NE,
                                      glog);
    k_scan<<<dim3(1), 256, 0, stream>>>(glog, srow, list, rnkl, cnt);
    k_mgemm<0><<<dim3(24, 16, 4), 256, 0, stream>>>(
        xn, w1 + (size_t)l * NE * D * DH, b1 + (size_t)l * NE * DH, hse, srow,
        list, rnkl, cnt);
    k_mgemm<1><<<dim3(6, 16, 4), 256, 0, stream>>>(
        hse, w2 + (size_t)l * NE * DH * D, nullptr, xc, srow, list, rnkl, cnt);
    k_moeadd<<<dim3(6144), 256, 0, stream>>>(x, xc, srow,
                                             b2 + (size_t)l * NE * D);
  }

  // ------------------------------------------------------------- head -------
  k_f2b<<<dim3(6144), 256, 0, stream>>>(x, xb);
  for (int half = 0; half < 2; ++half) {
    k_transpose<<<dim3(250, 12, 1), 256, 0, stream>>>(
        hw + half * 16000, (unsigned short*)hwT, V, D);
    k_bgemm<<<dim3(125, 16, 1), 256, 0, stream>>>(
        xb, hwT, hb + half * 16000, (float*)d_out + half * 16000, V, D);
  }
}

// Round 10
// 4403.181 us; speedup vs baseline: 3.0092x; 1.1929x over previous
//
#include <hip/hip_runtime.h>
#include <hip/hip_bf16.h>
#include <cstdint>
#include <cstddef>

typedef __hip_bfloat16 bf16;
typedef __attribute__((ext_vector_type(8))) short bf16x8;
typedef __attribute__((ext_vector_type(4))) float f32x4;

#define DEV __device__ __forceinline__

static constexpr int D  = 768;
static constexpr int NH = 12;
static constexpr int NE = 4;
static constexpr int DH = 3072;
static constexpr int L  = 1024;
static constexpr int T  = 2048;
static constexpr int V  = 32000;
static constexpr int NL = 4;

DEV bf16 f2b(float f) { return __float2bfloat16(f); }
DEV unsigned short f2bu(float f) {
  bf16 b = f2b(f);
  return *reinterpret_cast<unsigned short*>(&b);
}
DEV float gelu(float v) {
  return 0.5f * v * (1.f + erff(v * 0.70710678118654752f));
}

// ---------------------------------------------------------------- staging ----
DEV void gld16(const void* g, short* ldsbase, int lane) {
#if __has_builtin(__builtin_amdgcn_global_load_lds)
  (void)lane;
  __builtin_amdgcn_global_load_lds(
      (const __attribute__((address_space(1))) unsigned int*)g,
      (__attribute__((address_space(3))) unsigned int*)ldsbase, 16, 0, 0);
#else
  *reinterpret_cast<bf16x8*>(ldsbase + lane * 8) =
      *reinterpret_cast<const bf16x8*>(g);
#endif
}

// ------------------------------------------------------------- fp32 GEMM ----
// r5-proven structure: single-buffer LDS, BK=16, 128x128 tile, 8x8 microtile,
// 4+4-split COMP reads (2-way LDS, free).
// EPI: 1 = qkv (elu+1 for col<1536); 2 = out += acc+bias.
template <int EPI>
__global__ __launch_bounds__(256) void k_fgemm(
    const float* __restrict__ A, int lda,
    const float* __restrict__ B, int ldb,
    const float* __restrict__ bias,
    float* __restrict__ outp, int ldc,
    int Keff) {
  const int tid = threadIdx.x;
  const int tx = tid & 15;
  const int ty = tid >> 4;
  const int m0 = blockIdx.y * 128;
  const int n0 = blockIdx.x * 128;

  __shared__ float As[16 * 132];  // [kk][m]
  __shared__ float Bs[16 * 132];  // [kk][n]

  float acc[8][8];
#pragma unroll
  for (int i = 0; i < 8; ++i)
#pragma unroll
    for (int j = 0; j < 8; ++j) acc[i][j] = 0.f;

  const int sk = tid & 15;
  const int sm = tid >> 4;

  for (int kt = 0; kt < Keff; kt += 16) {
    __syncthreads();
#pragma unroll
    for (int i = 0; i < 8; ++i) {
      const int m = sm + 16 * i;
      As[sk * 132 + m] = A[(size_t)(m0 + m) * lda + kt + sk];
    }
#pragma unroll
    for (int i = 0; i < 8; ++i) {
      const int idx = tid + 256 * i;
      const int kk = idx >> 7, n = idx & 127;
      Bs[kk * 132 + n] = B[(size_t)(kt + kk) * ldb + n0 + n];
    }
    __syncthreads();

#pragma unroll
    for (int kk = 0; kk < 16; ++kk) {
      const float4 aLo = *(const float4*)&As[kk * 132 + ty * 4];
      const float4 aHi = *(const float4*)&As[kk * 132 + 64 + ty * 4];
      const float4 bLo = *(const float4*)&Bs[kk * 132 + tx * 4];
      const float4 bHi = *(const float4*)&Bs[kk * 132 + 64 + tx * 4];
      const float av[8] = {aLo.x, aLo.y, aLo.z, aLo.w,
                           aHi.x, aHi.y, aHi.z, aHi.w};
      const float bv[8] = {bLo.x, bLo.y, bLo.z, bLo.w,
                           bHi.x, bHi.y, bHi.z, bHi.w};
#pragma unroll
      for (int i = 0; i < 8; ++i)
#pragma unroll
        for (int j = 0; j < 8; ++j) acc[i][j] += av[i] * bv[j];
    }
  }

#pragma unroll
  for (int jh = 0; jh < 2; ++jh)
#pragma unroll
    for (int j = 0; j < 4; ++j) {
      const int col = n0 + jh * 64 + tx * 4 + j;
      const float bvl = bias[col];
#pragma unroll
      for (int ih = 0; ih < 2; ++ih)
#pragma unroll
        for (int i = 0; i < 4; ++i) {
          const int mm = m0 + ih * 64 + ty * 4 + i;
          const float v = acc[ih * 4 + i][jh * 4 + j] + bvl;
          const size_t idx = (size_t)mm * ldc + col;
          if constexpr (EPI == 1) {
            outp[idx] = (col < 1536) ? (v > 0.f ? v + 1.f : expf(v)) : v;
          } else {
            outp[idx] += v;
          }
        }
    }
}

// ------------------------------------------------------- sparse MoE GEMMs ---
// PH=0 (UP):   z = blockIdx.z (expert). hse[z][pos][3072] =
//              gelu(xn[list[z][pos]] @ w1[z] + b1[z]) * srow[tok][z]
// PH=1 (DOWN): blockIdx.z = expert*4 + kchunk (split-K over 3072 = 4x768).
//              xc[kchunk*2+rank][tok][768] = hse[z][pos] @ w2[z][kchunk-slice]
//              (separate buffers, fixed summation order -> deterministic)
// Both: 128x128 tile, BK=16, 4+4-split COMP, early-exit when m0 >= cnt[z].
template <int PH>
__global__ __launch_bounds__(256) void k_mgemm(
    const float* __restrict__ A, const float* __restrict__ B,
    const float* __restrict__ bias, float* __restrict__ outp,
    const float* __restrict__ srow, const int* __restrict__ list,
    const int* __restrict__ rnkl, const int* __restrict__ cnt) {
  const int zz = blockIdx.z;
  const int z  = (PH == 0) ? zz : (zz >> 2);
  const int kc = (PH == 0) ? 0 : (zz & 3);
  const int m0 = blockIdx.y * 128;
  const int cz = cnt[z];
  if (m0 >= cz) return;
  const int n0 = blockIdx.x * 128;
  constexpr int LDA = PH == 0 ? 768 : 3072;
  constexpr int LDB = PH == 0 ? 3072 : 768;
  const float* Bz = B + (size_t)z * (PH == 0 ? 768 : 3072) * LDB;
  const int kBeg = kc * 768;
  const int kEnd = kBeg + 768;

  const int tid = threadIdx.x;
  const int tx = tid & 15;
  const int ty = tid >> 4;

  __shared__ float As[16 * 132];
  __shared__ float Bs[16 * 132];
  __shared__ int rows[128];
  __shared__ int rnks[128];
  if (tid < 128) {
    rows[tid] = list[z * 2048 + m0 + tid];  // padded -> always valid token
    if (PH == 1) rnks[tid] = rnkl[z * 2048 + m0 + tid];
  }

  float acc[8][8];
#pragma unroll
  for (int i = 0; i < 8; ++i)
#pragma unroll
    for (int j = 0; j < 8; ++j) acc[i][j] = 0.f;

  const int sk = tid & 15;
  const int sm = tid >> 4;

  for (int kt = kBeg; kt < kEnd; kt += 16) {
    __syncthreads();
#pragma unroll
    for (int i = 0; i < 8; ++i) {
      const int m = sm + 16 * i;
      const int arow = (PH == 0) ? rows[m] : (z * 2048 + m0 + m);
      As[sk * 132 + m] = A[(size_t)arow * LDA + kt + sk];
    }
#pragma unroll
    for (int i = 0; i < 8; ++i) {
      const int idx = tid + 256 * i;
      const int kk = idx >> 7, n = idx & 127;
      Bs[kk * 132 + n] = Bz[(size_t)(kt + kk) * LDB + n0 + n];
    }
    __syncthreads();

#pragma unroll
    for (int kk = 0; kk < 16; ++kk) {
      const float4 aLo = *(const float4*)&As[kk * 132 + ty * 4];
      const float4 aHi = *(const float4*)&As[kk * 132 + 64 + ty * 4];
      const float4 bLo = *(const float4*)&Bs[kk * 132 + tx * 4];
      const float4 bHi = *(const float4*)&Bs[kk * 132 + 64 + tx * 4];
      const float av[8] = {aLo.x, aLo.y, aLo.z, aLo.w,
                           aHi.x, aHi.y, aHi.z, aHi.w};
      const float bv[8] = {bLo.x, bLo.y, bLo.z, bLo.w,
                           bHi.x, bHi.y, bHi.z, bHi.w};
#pragma unroll
      for (int i = 0; i < 8; ++i)
#pragma unroll
        for (int j = 0; j < 8; ++j) acc[i][j] += av[i] * bv[j];
    }
  }

#pragma unroll
  for (int ih = 0; ih < 2; ++ih)
#pragma unroll
    for (int i = 0; i < 4; ++i) {
      const int ml = ih * 64 + ty * 4 + i;  // local row in tile
      if constexpr (PH == 0) {
        const int pos = m0 + ml;
        const int tok = rows[ml];
        const float s = srow[tok * 4 + z];
        float* op = outp + ((size_t)z * 2048 + pos) * 3072;
#pragma unroll
        for (int jh = 0; jh < 2; ++jh)
#pragma unroll
          for (int j = 0; j < 4; ++j) {
            const int col = n0 + jh * 64 + tx * 4 + j;
            const float v = acc[ih * 4 + i][jh * 4 + j] + bias[z * 3072 + col];
            op[col] = s * gelu(v);
          }
      } else {
        if (m0 + ml < cz) {
          const int tok = rows[ml];
          const int rk = rnks[ml];
          float* op = outp + ((size_t)(kc * 2 + rk) * T + tok) * 768;
#pragma unroll
          for (int jh = 0; jh < 2; ++jh)
#pragma unroll
            for (int j = 0; j < 4; ++j) {
              const int col = n0 + jh * 64 + tx * 4 + j;
              op[col] = acc[ih * 4 + i][jh * 4 + j];
            }
        }
      }
    }
}

// ----------------------------------------------------- bf16 MFMA head GEMM --
__global__ __launch_bounds__(256) void k_bgemm(
    const bf16* __restrict__ A, const bf16* __restrict__ BT,
    const float* __restrict__ bias, float* __restrict__ outp,
    int ldc, int Keff) {
  const int tid  = threadIdx.x;
  const int wave = tid >> 6;
  const int lane = tid & 63;
  const int m0 = blockIdx.y * 128;
  const int n0 = blockIdx.x * 128;
  const int wm = (wave >> 1) * 64;
  const int wn = (wave & 1) * 64;
  const int ln = lane & 15;
  const int kg = lane >> 4;

  __shared__ short lds[8192];

  f32x4 acc[4][4] = {};

  const int rowA = lane >> 2;
  const int colK = (lane & 3) * 8;

  for (int kt = 0; kt < Keff; kt += 32) {
    __syncthreads();
#pragma unroll
    for (int c2 = 0; c2 < 2; ++c2) {
      const int chunk = c2 * 4 + wave;
      const int row = chunk * 16 + rowA;
      gld16(A + (size_t)(m0 + row) * 768 + kt + colK, &lds[chunk * 512], lane);
      gld16(BT + (size_t)(n0 + row) * 768 + kt + colK, &lds[4096 + chunk * 512],
            lane);
    }
    __syncthreads();

    bf16x8 af[4], bv[4];
#pragma unroll
    for (int r = 0; r < 4; ++r)
      af[r] = *reinterpret_cast<const bf16x8*>(
          &lds[(wm + r * 16 + ln) * 32 + kg * 8]);
#pragma unroll
    for (int c = 0; c < 4; ++c)
      bv[c] = *reinterpret_cast<const bf16x8*>(
          &lds[4096 + (wn + c * 16 + ln) * 32 + kg * 8]);

#pragma unroll
    for (int r = 0; r < 4; ++r)
#pragma unroll
      for (int c = 0; c < 4; ++c)
        acc[r][c] = __builtin_amdgcn_mfma_f32_16x16x32_bf16(
            af[r], bv[c], acc[r][c], 0, 0, 0);
  }

#pragma unroll
  for (int c = 0; c < 4; ++c) {
    const int nn = n0 + wn + c * 16 + ln;
    const float bvl = bias[nn];
#pragma unroll
    for (int r = 0; r < 4; ++r)
#pragma unroll
      for (int j = 0; j < 4; ++j) {
        const int mm = m0 + wm + r * 16 + kg * 4 + j;
        outp[(size_t)mm * ldc + nn] = acc[r][c][j] + bvl;
      }
  }
}

// -------------------------------------------------------------- transpose ----
__global__ __launch_bounds__(256) void k_transpose(
    const float* __restrict__ in, unsigned short* __restrict__ out,
    int C, int outStride) {
  __shared__ float t[64][65];
  const int tx = threadIdx.x & 15, ty = threadIdx.x >> 4;
  const int r0 = blockIdx.y * 64, c0 = blockIdx.x * 64;
#pragma unroll
  for (int i = 0; i < 4; ++i) {
    const int r = ty + i * 16;
    const float4 v = *(const float4*)&in[(size_t)(r0 + r) * C + c0 + tx * 4];
    t[r][tx * 4 + 0] = v.x;
    t[r][tx * 4 + 1] = v.y;
    t[r][tx * 4 + 2] = v.z;
    t[r][tx * 4 + 3] = v.w;
  }
  __syncthreads();
#pragma unroll
  for (int i = 0; i < 4; ++i) {
    const int a = ty + i * 16;
    ushort4 v;
    v.x = f2bu(t[tx * 4 + 0][a]);
    v.y = f2bu(t[tx * 4 + 1][a]);
    v.z = f2bu(t[tx * 4 + 2][a]);
    v.w = f2bu(t[tx * 4 + 3][a]);
    *(ushort4*)&out[(size_t)(c0 + a) * outStride + r0 + tx * 4] = v;
  }
}

// ------------------------------------------------------------ small kernels --
__global__ void k_embed(const int* __restrict__ tok,
                        const float* __restrict__ emb,
                        const float* __restrict__ pos, float* __restrict__ x) {
  const int idx = blockIdx.x * 256 + threadIdx.x;
  const int t = idx / D, d = idx - t * D;
  const int tk = tok[t];
  x[idx] = emb[(size_t)tk * D + d] + pos[(size_t)(t & (L - 1)) * D + d];
}

__global__ void k_f2b(const float* __restrict__ x, bf16* __restrict__ o) {
  const int idx = blockIdx.x * 256 + threadIdx.x;
  o[idx] = f2b(x[idx]);
}

// LayerNorm fp32->fp32. If gw != nullptr also emit fp32 gate logits (+gb).
__global__ __launch_bounds__(256) void k_ln(const float* __restrict__ x,
                                            const float* __restrict__ g,
                                            const float* __restrict__ bb,
                                            float* __restrict__ xn,
                                            const float* __restrict__ gw,
                                            const float* __restrict__ gb,
                                            float* __restrict__ glog) {
  const int row = blockIdx.x, tid = threadIdx.x;
  const float* xr = x + (size_t)row * D;
  const float v0 = xr[tid], v1 = xr[tid + 256], v2 = xr[tid + 512];
  float s = v0 + v1 + v2, s2 = v0 * v0 + v1 * v1 + v2 * v2;
  for (int off = 1; off < 64; off <<= 1) {
    s += __shfl_xor(s, off);
    s2 += __shfl_xor(s2, off);
  }
  __shared__ float rs[4], rs2[4];
  const int w = tid >> 6;
  if ((tid & 63) == 0) { rs[w] = s; rs2[w] = s2; }
  __syncthreads();
  const float S = rs[0] + rs[1] + rs[2] + rs[3];
  const float S2 = rs2[0] + rs2[1] + rs2[2] + rs2[3];
  const float mean = S * (1.f / 768.f);
  const float var = fmaxf(S2 * (1.f / 768.f) - mean * mean, 0.f);
  const float rstd = rsqrtf(var + 1e-5f);
  const float o0 = (v0 - mean) * rstd * g[tid]       + bb[tid];
  const float o1 = (v1 - mean) * rstd * g[tid + 256] + bb[tid + 256];
  const float o2 = (v2 - mean) * rstd * g[tid + 512] + bb[tid + 512];
  float* xo = xn + (size_t)row * D;
  xo[tid] = o0;
  xo[tid + 256] = o1;
  xo[tid + 512] = o2;

  if (gw != nullptr) {
    const float4 ga = *(const float4*)&gw[tid * 4];
    const float4 gbv = *(const float4*)&gw[(tid + 256) * 4];
    const float4 gc = *(const float4*)&gw[(tid + 512) * 4];
    float p0 = o0 * ga.x + o1 * gbv.x + o2 * gc.x;
    float p1 = o0 * ga.y + o1 * gbv.y + o2 * gc.y;
    float p2 = o0 * ga.z + o1 * gbv.z + o2 * gc.z;
    float p3 = o0 * ga.w + o1 * gbv.w + o2 * gc.w;
    for (int off = 1; off < 64; off <<= 1) {
      p0 += __shfl_xor(p0, off);
      p1 += __shfl_xor(p1, off);
      p2 += __shfl_xor(p2, off);
      p3 += __shfl_xor(p3, off);
    }
    __shared__ float rg[4][4];
    if ((tid & 63) == 0) {
      rg[w][0] = p0; rg[w][1] = p1; rg[w][2] = p2; rg[w][3] = p3;
    }
    __syncthreads();
    if (tid == 0) {
      float* gl = glog + (size_t)row * 4;
#pragma unroll
      for (int e = 0; e < 4; ++e)
        gl[e] = rg[0][e] + rg[1][e] + rg[2][e] + rg[3][e] + gb[e];
    }
  }
}

// top-2 softmax weights + deterministic per-expert token lists.
__global__ __launch_bounds__(256) void k_scan(const float* __restrict__ glog,
                                              float* __restrict__ srow,
                                              int* __restrict__ list,
                                              int* __restrict__ rnkl,
                                              int* __restrict__ cnt) {
  const int tid = threadIdx.x;
  __shared__ unsigned char e1s[2048], e2s[2048];
  for (int t = tid; t < T; t += 256) {
    float gv[4];
#pragma unroll
    for (int i = 0; i < 4; ++i) gv[i] = glog[t * 4 + i];
    int i1 = 0;
#pragma unroll
    for (int i = 1; i < 4; ++i)
      if (gv[i] > gv[i1]) i1 = i;
    int i2 = -1;
#pragma unroll
    for (int i = 0; i < 4; ++i) {
      if (i == i1) continue;
      if (i2 < 0 || gv[i] > gv[i2]) i2 = i;
    }
    const float e = expf(gv[i2] - gv[i1]);
    const float wa = 1.f / (1.f + e), wb = e / (1.f + e);
    float o[4] = {0.f, 0.f, 0.f, 0.f};
    o[i1] = wa;
    o[i2] = wb;
#pragma unroll
    for (int i = 0; i < 4; ++i) srow[t * 4 + i] = o[i];
    e1s[t] = (unsigned char)i1;
    e2s[t] = (unsigned char)i2;
  }
  __syncthreads();
  const int w = tid >> 6, lane = tid & 63;
  int base = 0;
  for (int c = 0; c < 32; ++c) {
    const int t = c * 64 + lane;
    const bool f1 = (e1s[t] == w);
    const bool f2 = (e2s[t] == w);
    const bool f = f1 || f2;
    const unsigned long long mask = __ballot(f);
    const int mypos = __popcll(mask & ((1ull << lane) - 1ull));
    if (f) {
      list[w * 2048 + base + mypos] = t;
      rnkl[w * 2048 + base + mypos] = f1 ? 0 : 1;
    }
    base += __popcll(mask);
  }
  if (lane == 0) cnt[w] = base;
  for (int ppos = base + lane; ppos < 2048; ppos += 64) {
    list[w * 2048 + ppos] = 0;
    rnkl[w * 2048 + ppos] = 0;
  }
}

// x += sum_{c=0..7} xc[c] + sum_e srow[t][e] * b2[e][n]  (fixed order)
__global__ void k_moeadd(float* __restrict__ x, const float* __restrict__ xc,
                         const float* __restrict__ srow,
                         const float* __restrict__ b2l) {
  const int idx = blockIdx.x * 256 + threadIdx.x;  // exactly T*D
  const int t = idx / D, n = idx - t * D;
  const float* s = srow + t * 4;
  float acc = x[idx];
#pragma unroll
  for (int c = 0; c < 8; ++c) acc += xc[(size_t)c * T * D + idx];
  acc += s[0] * b2l[n] + s[1] * b2l[D + n] + s[2] * b2l[2 * D + n] +
         s[3] * b2l[3 * D + n];
  x[idx] = acc;
}

__global__ void k_cat3(const float* __restrict__ a, const float* __restrict__ b,
                       const float* __restrict__ c, float* __restrict__ o) {
  const int i = blockIdx.x * 256 + threadIdx.x;
  o[i] = i < 768 ? a[i] : (i < 1536 ? b[i - 768] : c[i - 1536]);
}

__global__ void k_catW(const float* __restrict__ qw,
                       const float* __restrict__ kw,
                       const float* __restrict__ vw, float* __restrict__ o) {
  const int idx = blockIdx.x * 256 + threadIdx.x;
  const int k = idx / 2304, j = idx - k * 2304;
  float v;
  if (j < 768) v = qw[k * 768 + j];
  else if (j < 1536) v = kw[k * 768 + (j - 768)];
  else v = vw[k * 768 + (j - 1536)];
  o[idx] = v;
}

// Partial KV/Z over an L-chunk of 128 rows. part[c][bh][e*64+f], Z at +4096.
__global__ __launch_bounds__(256) void k_kvpart(const float* __restrict__ qkv,
                                                float* __restrict__ part) {
  const int bh = blockIdx.x;
  const int b = bh / NH, h = bh % NH;
  const int c = blockIdx.y;
  const int tid = threadIdx.x;
  __shared__ float kf[64], vv[64];
  float acc[16];
#pragma unroll
  for (int j = 0; j < 16; ++j) acc[j] = 0.f;
  float zacc = 0.f;
  const int e = tid >> 2;
  const int f0 = (tid & 3) * 16;
  const int t0 = b * L + c * 128;
  for (int i = 0; i < 128; ++i) {
    __syncthreads();
    const size_t rowb = (size_t)(t0 + i) * 2304;
    if (tid < 64) kf[tid] = qkv[rowb + 768 + h * 64 + tid];
    else if (tid < 128) vv[tid - 64] = qkv[rowb + 1536 + h * 64 + (tid - 64)];
    __syncthreads();
    const float ke = kf[e];
#pragma unroll
    for (int j = 0; j < 16; ++j) acc[j] += ke * vv[f0 + j];
    if (tid < 64) zacc += kf[tid];
  }
  const size_t base = ((size_t)c * 24 + bh) * 4160;
#pragma unroll
  for (int j = 0; j < 16; ++j) part[base + e * 64 + f0 + j] = acc[j];
  if (tid < 64) part[base + 4096 + tid] = zacc;
}

__global__ void k_kvred(const float* __restrict__ part, float* __restrict__ kv) {
  const int idx = blockIdx.x * 256 + threadIdx.x;
  float s = 0.f;
#pragma unroll
  for (int cc = 0; cc < 8; ++cc) s += part[(size_t)cc * 99840 + idx];
  kv[idx] = s;
}

__global__ __launch_bounds__(256) void k_attnout(const float* __restrict__ qkv,
                                                 const float* __restrict__ kv,
                                                 float* __restrict__ att) {
  const int t = blockIdx.x;
  const int b = t >> 10;
  const int tid = threadIdx.x;
  __shared__ float q[768];
  __shared__ float den[12];
  for (int i = tid; i < 768; i += 256) q[i] = qkv[(size_t)t * 2304 + i];
  __syncthreads();
  if (tid < 12) {
    const float* zz = kv + ((size_t)(b * NH + tid)) * 4160 + 4096;
    float s = 0.f;
#pragma unroll
    for (int e = 0; e < 64; ++e) s += q[tid * 64 + e] * zz[e];
    den[tid] = s + 1e-6f;
  }
  __syncthreads();
  for (int i = tid; i < 768; i += 256) {
    const int h = i >> 6, f = i & 63;
    const float* Kv = kv + ((size_t)(b * NH + h)) * 4160;
    float s = 0.f;
#pragma unroll
    for (int e = 0; e < 64; ++e) s += q[h * 64 + e] * Kv[e * 64 + f];
    att[(size_t)t * 768 + i] = s / den[h];
  }
}

// ------------------------------------------------------------------ launch ---
extern "C" void kernel_launch(void* const* d_in, const int* in_sizes, int n_in,
                              void* d_out, int out_size, void* d_ws,
                              size_t ws_size, hipStream_t stream) {
  const int*   tokens = (const int*)d_in[0];
  const float* emb  = (const float*)d_in[1];
  const float* pos  = (const float*)d_in[2];
  const float* qw   = (const float*)d_in[3];
  const float* qb   = (const float*)d_in[4];
  const float* kw   = (const float*)d_in[5];
  const float* kb   = (const float*)d_in[6];
  const float* vw   = (const float*)d_in[7];
  const float* vb   = (const float*)d_in[8];
  const float* ow   = (const float*)d_in[9];
  const float* ob   = (const float*)d_in[10];
  const float* ln1g = (const float*)d_in[11];
  const float* ln1b = (const float*)d_in[12];
  const float* ln2g = (const float*)d_in[13];
  const float* ln2b = (const float*)d_in[14];
  const float* gw   = (const float*)d_in[15];
  const float* gb   = (const float*)d_in[16];
  const float* w1   = (const float*)d_in[17];
  const float* b1   = (const float*)d_in[18];
  const float* w2   = (const float*)d_in[19];
  const float* b2   = (const float*)d_in[20];
  const float* hw   = (const float*)d_in[21];
  const float* hb   = (const float*)d_in[22];

  char* p = (char*)d_ws;
  auto alloc = [&](size_t bytes) -> void* {
    void* r = (void*)p;
    p += (bytes + 255) & ~((size_t)255);
    return r;
  };
  float* x    = (float*)alloc((size_t)T * D * 4);
  float* xn   = (float*)alloc((size_t)T * D * 4);
  float* qkvb = (float*)alloc((size_t)T * 2304 * 4);
  float* att  = (float*)alloc((size_t)T * D * 4);
  float* kvp  = (float*)alloc((size_t)8 * 24 * 4160 * 4);
  float* kv   = (float*)alloc((size_t)24 * 4160 * 4);
  float* srow = (float*)alloc((size_t)T * 4 * 4);
  float* glog = (float*)alloc((size_t)T * 4 * 4);
  float* bqkv = (float*)alloc((size_t)2304 * 4);
  float* wqkv = (float*)alloc((size_t)D * 2304 * 4);
  int*   list = (int*)alloc((size_t)NE * 2048 * 4);
  int*   rnkl = (int*)alloc((size_t)NE * 2048 * 4);
  int*   cnt  = (int*)alloc((size_t)16);
  // d_out (262 MB) scratch overlays, dead before the head writes it:
  //   hse [4][2048][3072] fp32 = 100.7 MB at offset 0
  //   xc  [8][T][768] fp32 = 50.3 MB after hse (4 kchunks x 2 ranks)
  float* hse = (float*)d_out;
  float* xc  = hse + (size_t)4 * 2048 * 3072;
  // Head-phase overlays in ws (dead regions): xb on xn; hwT on qkvb+att.
  bf16* xb  = (bf16*)xn;
  bf16* hwT = (bf16*)qkvb;

  k_embed<<<dim3(6144), 256, 0, stream>>>(tokens, emb, pos, x);

  for (int l = 0; l < NL; ++l) {
    const size_t DD = (size_t)D * D;
    k_catW<<<dim3(6912), 256, 0, stream>>>(qw + l * DD, kw + l * DD,
                                           vw + l * DD, wqkv);
    k_cat3<<<dim3(9), 256, 0, stream>>>(qb + l * D, kb + l * D, vb + l * D,
                                        bqkv);

    // attention
    k_ln<<<dim3(T), 256, 0, stream>>>(x, ln1g + l * D, ln1b + l * D, xn,
                                      nullptr, nullptr, nullptr);
    k_fgemm<1><<<dim3(18, 16, 1), 256, 0, stream>>>(
        xn, D, wqkv, 2304, bqkv, qkvb, 2304, D);
    k_kvpart<<<dim3(24, 8), 256, 0, stream>>>(qkvb, kvp);
    k_kvred<<<dim3(390), 256, 0, stream>>>(kvp, kv);
    k_attnout<<<dim3(T), 256, 0, stream>>>(qkvb, kv, att);
    k_fgemm<2><<<dim3(6, 16, 1), 256, 0, stream>>>(
        att, D, ow + l * DD, D, ob + l * D, x, D, D);

    // MoE (sparse top-2, exact fp32; DOWN split-K for occupancy)
    k_ln<<<dim3(T), 256, 0, stream>>>(x, ln2g + l * D, ln2b + l * D, xn,
                                      gw + (size_t)l * D * NE, gb + l * NE,
                                      glog);
    k_scan<<<dim3(1), 256, 0, stream>>>(glog, srow, list, rnkl, cnt);
    k_mgemm<0><<<dim3(24, 16, 4), 256, 0, stream>>>(
        xn, w1 + (size_t)l * NE * D * DH, b1 + (size_t)l * NE * DH, hse, srow,
        list, rnkl, cnt);
    k_mgemm<1><<<dim3(6, 16, 16), 256, 0, stream>>>(
        hse, w2 + (size_t)l * NE * DH * D, nullptr, xc, srow, list, rnkl, cnt);
    k_moeadd<<<dim3(6144), 256, 0, stream>>>(x, xc, srow,
                                             b2 + (size_t)l * NE * D);
  }

  // ------------------------------------------------------------- head -------
  k_f2b<<<dim3(6144), 256, 0, stream>>>(x, xb);
  for (int half = 0; half < 2; ++half) {
    k_transpose<<<dim3(250, 12, 1), 256, 0, stream>>>(
        hw + half * 16000, (unsigned short*)hwT, V, D);
    k_bgemm<<<dim3(125, 16, 1), 256, 0, stream>>>(
        xb, hwT, hb + half * 16000, (float*)d_out + half * 16000, V, D);
  }
}

// Round 11
// 3309.271 us; speedup vs baseline: 4.0039x; 1.3306x over previous
//
#include <hip/hip_runtime.h>
#include <hip/hip_bf16.h>
#include <cstdint>
#include <cstddef>

typedef __hip_bfloat16 bf16;
typedef __attribute__((ext_vector_type(8))) short bf16x8;
typedef __attribute__((ext_vector_type(4))) float f32x4;

#define DEV __device__ __forceinline__

static constexpr int D  = 768;
static constexpr int NH = 12;
static constexpr int NE = 4;
static constexpr int DH = 3072;
static constexpr int L  = 1024;
static constexpr int T  = 2048;
static constexpr int V  = 32000;
static constexpr int NL = 4;

static constexpr long PSX = (long)T * 768;        // xn plane stride (el)
static constexpr long PSH = (long)NE * 2048 * DH; // hse plane stride (el)
static constexpr long PSW = (long)NE * DH * 768;  // weight plane stride (el)
static constexpr long EB  = (long)DH * 768;       // per-expert weight (el)

DEV float b2f(bf16 v) { return __bfloat162float(v); }
DEV bf16 f2b(float f) { return __float2bfloat16(f); }
DEV unsigned short f2bu(float f) {
  bf16 b = f2b(f);
  return *reinterpret_cast<unsigned short*>(&b);
}
DEV float gelu(float v) {
  return 0.5f * v * (1.f + erff(v * 0.70710678118654752f));
}
// Exact fp32 -> 3x bf16 plane decomposition (a ~= p0+p1+p2 to ~2^-24).
DEV void split3u(float a, unsigned short& x0, unsigned short& x1,
                 unsigned short& x2) {
  bf16 c0 = f2b(a);
  float r1 = a - b2f(c0);
  bf16 c1 = f2b(r1);
  float r2 = r1 - b2f(c1);
  bf16 c2 = f2b(r2);
  x0 = *reinterpret_cast<unsigned short*>(&c0);
  x1 = *reinterpret_cast<unsigned short*>(&c1);
  x2 = *reinterpret_cast<unsigned short*>(&c2);
}

// ---------------------------------------------------------------- staging ----
DEV void gld16(const void* g, short* ldsbase, int lane) {
#if __has_builtin(__builtin_amdgcn_global_load_lds)
  (void)lane;
  __builtin_amdgcn_global_load_lds(
      (const __attribute__((address_space(1))) unsigned int*)g,
      (__attribute__((address_space(3))) unsigned int*)ldsbase, 16, 0, 0);
#else
  *reinterpret_cast<bf16x8*>(ldsbase + lane * 8) =
      *reinterpret_cast<const bf16x8*>(g);
#endif
}

// ------------------------------------------------------------- fp32 GEMM ----
// r5-proven structure (single-buffer, BK=16, 128x128, 8x8 microtile, 4+4 COMP).
// EPI: 1 = qkv (elu+1 for col<1536); 2 = out += acc+bias.
template <int EPI>
__global__ __launch_bounds__(256) void k_fgemm(
    const float* __restrict__ A, int lda,
    const float* __restrict__ B, int ldb,
    const float* __restrict__ bias,
    float* __restrict__ outp, int ldc,
    int Keff) {
  const int tid = threadIdx.x;
  const int tx = tid & 15;
  const int ty = tid >> 4;
  const int m0 = blockIdx.y * 128;
  const int n0 = blockIdx.x * 128;

  __shared__ float As[16 * 132];
  __shared__ float Bs[16 * 132];

  float acc[8][8];
#pragma unroll
  for (int i = 0; i < 8; ++i)
#pragma unroll
    for (int j = 0; j < 8; ++j) acc[i][j] = 0.f;

  const int sk = tid & 15;
  const int sm = tid >> 4;

  for (int kt = 0; kt < Keff; kt += 16) {
    __syncthreads();
#pragma unroll
    for (int i = 0; i < 8; ++i) {
      const int m = sm + 16 * i;
      As[sk * 132 + m] = A[(size_t)(m0 + m) * lda + kt + sk];
    }
#pragma unroll
    for (int i = 0; i < 8; ++i) {
      const int idx = tid + 256 * i;
      const int kk = idx >> 7, n = idx & 127;
      Bs[kk * 132 + n] = B[(size_t)(kt + kk) * ldb + n0 + n];
    }
    __syncthreads();

#pragma unroll
    for (int kk = 0; kk < 16; ++kk) {
      const float4 aLo = *(const float4*)&As[kk * 132 + ty * 4];
      const float4 aHi = *(const float4*)&As[kk * 132 + 64 + ty * 4];
      const float4 bLo = *(const float4*)&Bs[kk * 132 + tx * 4];
      const float4 bHi = *(const float4*)&Bs[kk * 132 + 64 + tx * 4];
      const float av[8] = {aLo.x, aLo.y, aLo.z, aLo.w,
                           aHi.x, aHi.y, aHi.z, aHi.w};
      const float bv[8] = {bLo.x, bLo.y, bLo.z, bLo.w,
                           bHi.x, bHi.y, bHi.z, bHi.w};
#pragma unroll
      for (int i = 0; i < 8; ++i)
#pragma unroll
        for (int j = 0; j < 8; ++j) acc[i][j] += av[i] * bv[j];
    }
  }

#pragma unroll
  for (int jh = 0; jh < 2; ++jh)
#pragma unroll
    for (int j = 0; j < 4; ++j) {
      const int col = n0 + jh * 64 + tx * 4 + j;
      const float bvl = bias[col];
#pragma unroll
      for (int ih = 0; ih < 2; ++ih)
#pragma unroll
        for (int i = 0; i < 4; ++i) {
          const int mm = m0 + ih * 64 + ty * 4 + i;
          const float v = acc[ih * 4 + i][jh * 4 + j] + bvl;
          const size_t idx = (size_t)mm * ldc + col;
          if constexpr (EPI == 1) {
            outp[idx] = (col < 1536) ? (v > 0.f ? v + 1.f : expf(v)) : v;
          } else {
            outp[idx] += v;
          }
        }
    }
}

// ----------------------------------------- bf16x3 split-precision MoE GEMM --
// fp32-faithful MFMA: A,B each in 3 bf16 planes; 6 cross products (i+j<=2)
// reproduce fp32 to ~2^-24. Fragment/staging layout = verified k_bgemm.
// PH=0 (UP):  A = xn planes, rows gathered via list[z]; out = hse planes
//             (gelu(acc+b1)*srow, split3). Grid (24,16,4).
// PH=1 (DOWN):A = hse planes (linear rows); split-K: blockIdx.z = z*4+kc;
//             out xc[(kc*2+rank)][tok][768] fp32. Grid (6,16,16).
template <int PH>
__global__ __launch_bounds__(256) void k_moe3(
    const bf16* __restrict__ Ap, long psA,
    const bf16* __restrict__ Bp, long psB,
    const float* __restrict__ b1z,
    bf16* __restrict__ hseP,
    float* __restrict__ xc,
    const float* __restrict__ srow, const int* __restrict__ list,
    const int* __restrict__ rnkl, const int* __restrict__ cnt) {
  const int zz = blockIdx.z;
  const int z  = (PH == 0) ? zz : (zz >> 2);
  const int kc = (PH == 0) ? 0 : (zz & 3);
  const int m0 = blockIdx.y * 128;
  const int cz = cnt[z];
  if (m0 >= cz) return;
  const int n0 = blockIdx.x * 128;
  constexpr int LD = PH ? 3072 : 768;  // row length (K) for both A and B^T
  const int kBeg = kc * 768;

  const int tid  = threadIdx.x;
  const int wave = tid >> 6;
  const int lane = tid & 63;
  const int wm = (wave >> 1) * 64;
  const int wn = (wave & 1) * 64;
  const int ln = lane & 15;
  const int kg = lane >> 4;
  const int rowA = lane >> 2;
  const int colK = (lane & 3) * 8;

  __shared__ short lds[24576];  // A planes @0/4096/8192, B planes @12288+...
  __shared__ int rows[128];
  __shared__ int rnks[128];
  if (tid < 128) {
    rows[tid] = list[z * 2048 + m0 + tid];
    if (PH == 1) rnks[tid] = rnkl[z * 2048 + m0 + tid];
  }

  f32x4 acc[4][4] = {};
  const bf16* Bz = Bp + (size_t)z * EB;

  for (int kt = kBeg; kt < kBeg + 768; kt += 32) {
    __syncthreads();
#pragma unroll
    for (int c2 = 0; c2 < 2; ++c2) {
      const int chunk = c2 * 4 + wave;
      const int r16 = chunk * 16 + rowA;
      const size_t arow =
          (PH == 0) ? (size_t)rows[r16] : (size_t)(z * 2048 + m0 + r16);
      const size_t brow = (size_t)(n0 + r16);
#pragma unroll
      for (int p = 0; p < 3; ++p) {
        gld16(Ap + (size_t)p * psA + arow * LD + kt + colK,
              &lds[p * 4096 + chunk * 512], lane);
        gld16(Bz + (size_t)p * psB + brow * LD + kt + colK,
              &lds[12288 + p * 4096 + chunk * 512], lane);
      }
    }
    __syncthreads();

    bf16x8 af[3][4];
#pragma unroll
    for (int r = 0; r < 4; ++r)
#pragma unroll
      for (int p = 0; p < 3; ++p)
        af[p][r] = *reinterpret_cast<const bf16x8*>(
            &lds[p * 4096 + (wm + r * 16 + ln) * 32 + kg * 8]);

#pragma unroll
    for (int c = 0; c < 4; ++c) {
      const int bo = (wn + c * 16 + ln) * 32 + kg * 8;
      const bf16x8 bv0 =
          *reinterpret_cast<const bf16x8*>(&lds[12288 + bo]);
      const bf16x8 bv1 =
          *reinterpret_cast<const bf16x8*>(&lds[12288 + 4096 + bo]);
      const bf16x8 bv2 =
          *reinterpret_cast<const bf16x8*>(&lds[12288 + 8192 + bo]);
#pragma unroll
      for (int r = 0; r < 4; ++r) {
        f32x4 a = acc[r][c];
        a = __builtin_amdgcn_mfma_f32_16x16x32_bf16(af[0][r], bv0, a, 0, 0, 0);
        a = __builtin_amdgcn_mfma_f32_16x16x32_bf16(af[0][r], bv1, a, 0, 0, 0);
        a = __builtin_amdgcn_mfma_f32_16x16x32_bf16(af[1][r], bv0, a, 0, 0, 0);
        a = __builtin_amdgcn_mfma_f32_16x16x32_bf16(af[0][r], bv2, a, 0, 0, 0);
        a = __builtin_amdgcn_mfma_f32_16x16x32_bf16(af[1][r], bv1, a, 0, 0, 0);
        a = __builtin_amdgcn_mfma_f32_16x16x32_bf16(af[2][r], bv0, a, 0, 0, 0);
        acc[r][c] = a;
      }
    }
  }

  // epilogue (C/D mapping verified: col = n0+wn+c*16+ln, row = wm+r*16+kg*4+j)
#pragma unroll
  for (int c = 0; c < 4; ++c) {
    const int col = n0 + wn + c * 16 + ln;
    float bvl = 0.f;
    if constexpr (PH == 0) bvl = b1z[z * 3072 + col];
#pragma unroll
    for (int r = 0; r < 4; ++r)
#pragma unroll
      for (int j = 0; j < 4; ++j) {
        const int rl = wm + r * 16 + kg * 4 + j;
        if constexpr (PH == 0) {
          const int pos = m0 + rl;
          const int tok = rows[rl];
          const float s = srow[tok * 4 + z];
          const float h = s * gelu(acc[r][c][j] + bvl);
          unsigned short u0, u1, u2;
          split3u(h, u0, u1, u2);
          unsigned short* hp = (unsigned short*)hseP;
          const size_t o = ((size_t)z * 2048 + pos) * 3072 + col;
          hp[o] = u0;
          hp[PSH + o] = u1;
          hp[2 * PSH + o] = u2;
        } else {
          if (m0 + rl < cz) {
            const int tok = rows[rl];
            const int rk = rnks[rl];
            xc[((size_t)(kc * 2 + rk) * T + tok) * 768 + col] = acc[r][c][j];
          }
        }
      }
  }
}

// ----------------------------------------------------- bf16 MFMA head GEMM --
__global__ __launch_bounds__(256) void k_bgemm(
    const bf16* __restrict__ A, const bf16* __restrict__ BT,
    const float* __restrict__ bias, float* __restrict__ outp,
    int ldc, int Keff) {
  const int tid  = threadIdx.x;
  const int wave = tid >> 6;
  const int lane = tid & 63;
  const int m0 = blockIdx.y * 128;
  const int n0 = blockIdx.x * 128;
  const int wm = (wave >> 1) * 64;
  const int wn = (wave & 1) * 64;
  const int ln = lane & 15;
  const int kg = lane >> 4;

  __shared__ short lds[8192];

  f32x4 acc[4][4] = {};

  const int rowA = lane >> 2;
  const int colK = (lane & 3) * 8;

  for (int kt = 0; kt < Keff; kt += 32) {
    __syncthreads();
#pragma unroll
    for (int c2 = 0; c2 < 2; ++c2) {
      const int chunk = c2 * 4 + wave;
      const int row = chunk * 16 + rowA;
      gld16(A + (size_t)(m0 + row) * 768 + kt + colK, &lds[chunk * 512], lane);
      gld16(BT + (size_t)(n0 + row) * 768 + kt + colK, &lds[4096 + chunk * 512],
            lane);
    }
    __syncthreads();

    bf16x8 af[4], bv[4];
#pragma unroll
    for (int r = 0; r < 4; ++r)
      af[r] = *reinterpret_cast<const bf16x8*>(
          &lds[(wm + r * 16 + ln) * 32 + kg * 8]);
#pragma unroll
    for (int c = 0; c < 4; ++c)
      bv[c] = *reinterpret_cast<const bf16x8*>(
          &lds[4096 + (wn + c * 16 + ln) * 32 + kg * 8]);

#pragma unroll
    for (int r = 0; r < 4; ++r)
#pragma unroll
      for (int c = 0; c < 4; ++c)
        acc[r][c] = __builtin_amdgcn_mfma_f32_16x16x32_bf16(
            af[r], bv[c], acc[r][c], 0, 0, 0);
  }

#pragma unroll
  for (int c = 0; c < 4; ++c) {
    const int nn = n0 + wn + c * 16 + ln;
    const float bvl = bias[nn];
#pragma unroll
    for (int r = 0; r < 4; ++r)
#pragma unroll
      for (int j = 0; j < 4; ++j) {
        const int mm = m0 + wm + r * 16 + kg * 4 + j;
        outp[(size_t)mm * ldc + nn] = acc[r][c][j] + bvl;
      }
  }
}

// -------------------------------------------------------------- transposes ---
// fp32 [R][C] -> bf16 [C][R] (head weights)
__global__ __launch_bounds__(256) void k_transpose(
    const float* __restrict__ in, unsigned short* __restrict__ out,
    int C, int outStride) {
  __shared__ float t[64][65];
  const int tx = threadIdx.x & 15, ty = threadIdx.x >> 4;
  const int r0 = blockIdx.y * 64, c0 = blockIdx.x * 64;
#pragma unroll
  for (int i = 0; i < 4; ++i) {
    const int r = ty + i * 16;
    const float4 v = *(const float4*)&in[(size_t)(r0 + r) * C + c0 + tx * 4];
    t[r][tx * 4 + 0] = v.x;
    t[r][tx * 4 + 1] = v.y;
    t[r][tx * 4 + 2] = v.z;
    t[r][tx * 4 + 3] = v.w;
  }
  __syncthreads();
#pragma unroll
  for (int i = 0; i < 4; ++i) {
    const int a = ty + i * 16;
    ushort4 v;
    v.x = f2bu(t[tx * 4 + 0][a]);
    v.y = f2bu(t[tx * 4 + 1][a]);
    v.z = f2bu(t[tx * 4 + 2][a]);
    v.w = f2bu(t[tx * 4 + 3][a]);
    *(ushort4*)&out[(size_t)(c0 + a) * outStride + r0 + tx * 4] = v;
  }
}

// fp32 [R][C] -> 3x bf16 planes [C][R] (weight split for k_moe3), z experts.
__global__ __launch_bounds__(256) void k_tsplit3(
    const float* __restrict__ in, long inE,
    unsigned short* __restrict__ out, long outE, long planeS,
    int C, int outStride) {
  in += (size_t)blockIdx.z * inE;
  unsigned short* o = out + (size_t)blockIdx.z * outE;
  __shared__ float t[64][65];
  const int tx = threadIdx.x & 15, ty = threadIdx.x >> 4;
  const int r0 = blockIdx.y * 64, c0 = blockIdx.x * 64;
#pragma unroll
  for (int i = 0; i < 4; ++i) {
    const int r = ty + i * 16;
    const float4 v = *(const float4*)&in[(size_t)(r0 + r) * C + c0 + tx * 4];
    t[r][tx * 4 + 0] = v.x;
    t[r][tx * 4 + 1] = v.y;
    t[r][tx * 4 + 2] = v.z;
    t[r][tx * 4 + 3] = v.w;
  }
  __syncthreads();
#pragma unroll
  for (int i = 0; i < 4; ++i) {
    const int a = ty + i * 16;
    ushort4 u0, u1, u2;
    split3u(t[tx * 4 + 0][a], u0.x, u1.x, u2.x);
    split3u(t[tx * 4 + 1][a], u0.y, u1.y, u2.y);
    split3u(t[tx * 4 + 2][a], u0.z, u1.z, u2.z);
    split3u(t[tx * 4 + 3][a], u0.w, u1.w, u2.w);
    const size_t off = (size_t)(c0 + a) * outStride + r0 + tx * 4;
    *(ushort4*)&o[off] = u0;
    *(ushort4*)&o[planeS + off] = u1;
    *(ushort4*)&o[2 * planeS + off] = u2;
  }
}

// ------------------------------------------------------------ small kernels --
__global__ void k_embed(const int* __restrict__ tok,
                        const float* __restrict__ emb,
                        const float* __restrict__ pos, float* __restrict__ x) {
  const int idx = blockIdx.x * 256 + threadIdx.x;
  const int t = idx / D, d = idx - t * D;
  const int tk = tok[t];
  x[idx] = emb[(size_t)tk * D + d] + pos[(size_t)(t & (L - 1)) * D + d];
}

__global__ void k_f2b(const float* __restrict__ x, bf16* __restrict__ o) {
  const int idx = blockIdx.x * 256 + threadIdx.x;
  o[idx] = f2b(x[idx]);
}

// LayerNorm fp32 in. Outputs: xnf (fp32, may be null) and/or xnp (3x bf16
// planes, may be null). If gw != null also emit fp32 gate logits (+gb).
__global__ __launch_bounds__(256) void k_ln(const float* __restrict__ x,
                                            const float* __restrict__ g,
                                            const float* __restrict__ bb,
                                            float* __restrict__ xnf,
                                            unsigned short* __restrict__ xnp,
                                            const float* __restrict__ gw,
                                            const float* __restrict__ gb,
                                            float* __restrict__ glog) {
  const int row = blockIdx.x, tid = threadIdx.x;
  const float* xr = x + (size_t)row * D;
  const float v0 = xr[tid], v1 = xr[tid + 256], v2 = xr[tid + 512];
  float s = v0 + v1 + v2, s2 = v0 * v0 + v1 * v1 + v2 * v2;
  for (int off = 1; off < 64; off <<= 1) {
    s += __shfl_xor(s, off);
    s2 += __shfl_xor(s2, off);
  }
  __shared__ float rs[4], rs2[4];
  const int w = tid >> 6;
  if ((tid & 63) == 0) { rs[w] = s; rs2[w] = s2; }
  __syncthreads();
  const float S = rs[0] + rs[1] + rs[2] + rs[3];
  const float S2 = rs2[0] + rs2[1] + rs2[2] + rs2[3];
  const float mean = S * (1.f / 768.f);
  const float var = fmaxf(S2 * (1.f / 768.f) - mean * mean, 0.f);
  const float rstd = rsqrtf(var + 1e-5f);
  const float o0 = (v0 - mean) * rstd * g[tid]       + bb[tid];
  const float o1 = (v1 - mean) * rstd * g[tid + 256] + bb[tid + 256];
  const float o2 = (v2 - mean) * rstd * g[tid + 512] + bb[tid + 512];
  if (xnf != nullptr) {
    float* xo = xnf + (size_t)row * D;
    xo[tid] = o0;
    xo[tid + 256] = o1;
    xo[tid + 512] = o2;
  }
  if (xnp != nullptr) {
    const size_t base = (size_t)row * D;
    unsigned short a0, a1, a2;
    split3u(o0, a0, a1, a2);
    xnp[base + tid] = a0;
    xnp[PSX + base + tid] = a1;
    xnp[2 * PSX + base + tid] = a2;
    split3u(o1, a0, a1, a2);
    xnp[base + tid + 256] = a0;
    xnp[PSX + base + tid + 256] = a1;
    xnp[2 * PSX + base + tid + 256] = a2;
    split3u(o2, a0, a1, a2);
    xnp[base + tid + 512] = a0;
    xnp[PSX + base + tid + 512] = a1;
    xnp[2 * PSX + base + tid + 512] = a2;
  }

  if (gw != nullptr) {
    const float4 ga = *(const float4*)&gw[tid * 4];
    const float4 gbv = *(const float4*)&gw[(tid + 256) * 4];
    const float4 gc = *(const float4*)&gw[(tid + 512) * 4];
    float p0 = o0 * ga.x + o1 * gbv.x + o2 * gc.x;
    float p1 = o0 * ga.y + o1 * gbv.y + o2 * gc.y;
    float p2 = o0 * ga.z + o1 * gbv.z + o2 * gc.z;
    float p3 = o0 * ga.w + o1 * gbv.w + o2 * gc.w;
    for (int off = 1; off < 64; off <<= 1) {
      p0 += __shfl_xor(p0, off);
      p1 += __shfl_xor(p1, off);
      p2 += __shfl_xor(p2, off);
      p3 += __shfl_xor(p3, off);
    }
    __shared__ float rg[4][4];
    if ((tid & 63) == 0) {
      rg[w][0] = p0; rg[w][1] = p1; rg[w][2] = p2; rg[w][3] = p3;
    }
    __syncthreads();
    if (tid == 0) {
      float* gl = glog + (size_t)row * 4;
#pragma unroll
      for (int e = 0; e < 4; ++e)
        gl[e] = rg[0][e] + rg[1][e] + rg[2][e] + rg[3][e] + gb[e];
    }
  }
}

// top-2 softmax weights + deterministic per-expert token lists.
__global__ __launch_bounds__(256) void k_scan(const float* __restrict__ glog,
                                              float* __restrict__ srow,
                                              int* __restrict__ list,
                                              int* __restrict__ rnkl,
                                              int* __restrict__ cnt) {
  const int tid = threadIdx.x;
  __shared__ unsigned char e1s[2048], e2s[2048];
  for (int t = tid; t < T; t += 256) {
    float gv[4];
#pragma unroll
    for (int i = 0; i < 4; ++i) gv[i] = glog[t * 4 + i];
    int i1 = 0;
#pragma unroll
    for (int i = 1; i < 4; ++i)
      if (gv[i] > gv[i1]) i1 = i;
    int i2 = -1;
#pragma unroll
    for (int i = 0; i < 4; ++i) {
      if (i == i1) continue;
      if (i2 < 0 || gv[i] > gv[i2]) i2 = i;
    }
    const float e = expf(gv[i2] - gv[i1]);
    const float wa = 1.f / (1.f + e), wb = e / (1.f + e);
    float o[4] = {0.f, 0.f, 0.f, 0.f};
    o[i1] = wa;
    o[i2] = wb;
#pragma unroll
    for (int i = 0; i < 4; ++i) srow[t * 4 + i] = o[i];
    e1s[t] = (unsigned char)i1;
    e2s[t] = (unsigned char)i2;
  }
  __syncthreads();
  const int w = tid >> 6, lane = tid & 63;
  int base = 0;
  for (int c = 0; c < 32; ++c) {
    const int t = c * 64 + lane;
    const bool f1 = (e1s[t] == w);
    const bool f2 = (e2s[t] == w);
    const bool f = f1 || f2;
    const unsigned long long mask = __ballot(f);
    const int mypos = __popcll(mask & ((1ull << lane) - 1ull));
    if (f) {
      list[w * 2048 + base + mypos] = t;
      rnkl[w * 2048 + base + mypos] = f1 ? 0 : 1;
    }
    base += __popcll(mask);
  }
  if (lane == 0) cnt[w] = base;
  for (int ppos = base + lane; ppos < 2048; ppos += 64) {
    list[w * 2048 + ppos] = 0;
    rnkl[w * 2048 + ppos] = 0;
  }
}

// x += sum_{c=0..7} xc[c] + sum_e srow[t][e] * b2[e][n]  (fixed order)
__global__ void k_moeadd(float* __restrict__ x, const float* __restrict__ xc,
                         const float* __restrict__ srow,
                         const float* __restrict__ b2l) {
  const int idx = blockIdx.x * 256 + threadIdx.x;
  const int t = idx / D, n = idx - t * D;
  const float* s = srow + t * 4;
  float acc = x[idx];
#pragma unroll
  for (int c = 0; c < 8; ++c) acc += xc[(size_t)c * T * D + idx];
  acc += s[0] * b2l[n] + s[1] * b2l[D + n] + s[2] * b2l[2 * D + n] +
         s[3] * b2l[3 * D + n];
  x[idx] = acc;
}

__global__ void k_cat3(const float* __restrict__ a, const float* __restrict__ b,
                       const float* __restrict__ c, float* __restrict__ o) {
  const int i = blockIdx.x * 256 + threadIdx.x;
  o[i] = i < 768 ? a[i] : (i < 1536 ? b[i - 768] : c[i - 1536]);
}

__global__ void k_catW(const float* __restrict__ qw,
                       const float* __restrict__ kw,
                       const float* __restrict__ vw, float* __restrict__ o) {
  const int idx = blockIdx.x * 256 + threadIdx.x;
  const int k = idx / 2304, j = idx - k * 2304;
  float v;
  if (j < 768) v = qw[k * 768 + j];
  else if (j < 1536) v = kw[k * 768 + (j - 768)];
  else v = vw[k * 768 + (j - 1536)];
  o[idx] = v;
}

// Partial KV/Z over an L-chunk of 128 rows. part[c][bh][e*64+f], Z at +4096.
__global__ __launch_bounds__(256) void k_kvpart(const float* __restrict__ qkv,
                                                float* __restrict__ part) {
  const int bh = blockIdx.x;
  const int b = bh / NH, h = bh % NH;
  const int c = blockIdx.y;
  const int tid = threadIdx.x;
  __shared__ float kf[64], vv[64];
  float acc[16];
#pragma unroll
  for (int j = 0; j < 16; ++j) acc[j] = 0.f;
  float zacc = 0.f;
  const int e = tid >> 2;
  const int f0 = (tid & 3) * 16;
  const int t0 = b * L + c * 128;
  for (int i = 0; i < 128; ++i) {
    __syncthreads();
    const size_t rowb = (size_t)(t0 + i) * 2304;
    if (tid < 64) kf[tid] = qkv[rowb + 768 + h * 64 + tid];
    else if (tid < 128) vv[tid - 64] = qkv[rowb + 1536 + h * 64 + (tid - 64)];
    __syncthreads();
    const float ke = kf[e];
#pragma unroll
    for (int j = 0; j < 16; ++j) acc[j] += ke * vv[f0 + j];
    if (tid < 64) zacc += kf[tid];
  }
  const size_t base = ((size_t)c * 24 + bh) * 4160;
#pragma unroll
  for (int j = 0; j < 16; ++j) part[base + e * 64 + f0 + j] = acc[j];
  if (tid < 64) part[base + 4096 + tid] = zacc;
}

__global__ void k_kvred(const float* __restrict__ part, float* __restrict__ kv) {
  const int idx = blockIdx.x * 256 + threadIdx.x;
  float s = 0.f;
#pragma unroll
  for (int cc = 0; cc < 8; ++cc) s += part[(size_t)cc * 99840 + idx];
  kv[idx] = s;
}

__global__ __launch_bounds__(256) void k_attnout(const float* __restrict__ qkv,
                                                 const float* __restrict__ kv,
                                                 float* __restrict__ att) {
  const int t = blockIdx.x;
  const int b = t >> 10;
  const int tid = threadIdx.x;
  __shared__ float q[768];
  __shared__ float den[12];
  for (int i = tid; i < 768; i += 256) q[i] = qkv[(size_t)t * 2304 + i];
  __syncthreads();
  if (tid < 12) {
    const float* zz = kv + ((size_t)(b * NH + tid)) * 4160 + 4096;
    float s = 0.f;
#pragma unroll
    for (int e = 0; e < 64; ++e) s += q[tid * 64 + e] * zz[e];
    den[tid] = s + 1e-6f;
  }
  __syncthreads();
  for (int i = tid; i < 768; i += 256) {
    const int h = i >> 6, f = i & 63;
    const float* Kv = kv + ((size_t)(b * NH + h)) * 4160;
    float s = 0.f;
#pragma unroll
    for (int e = 0; e < 64; ++e) s += q[h * 64 + e] * Kv[e * 64 + f];
    att[(size_t)t * 768 + i] = s / den[h];
  }
}

// ------------------------------------------------------------------ launch ---
extern "C" void kernel_launch(void* const* d_in, const int* in_sizes, int n_in,
                              void* d_out, int out_size, void* d_ws,
                              size_t ws_size, hipStream_t stream) {
  const int*   tokens = (const int*)d_in[0];
  const float* emb  = (const float*)d_in[1];
  const float* pos  = (const float*)d_in[2];
  const float* qw   = (const float*)d_in[3];
  const float* qb   = (const float*)d_in[4];
  const float* kw   = (const float*)d_in[5];
  const float* kb   = (const float*)d_in[6];
  const float* vw   = (const float*)d_in[7];
  const float* vb   = (const float*)d_in[8];
  const float* ow   = (const float*)d_in[9];
  const float* ob   = (const float*)d_in[10];
  const float* ln1g = (const float*)d_in[11];
  const float* ln1b = (const float*)d_in[12];
  const float* ln2g = (const float*)d_in[13];
  const float* ln2b = (const float*)d_in[14];
  const float* gw   = (const float*)d_in[15];
  const float* gb   = (const float*)d_in[16];
  const float* w1   = (const float*)d_in[17];
  const float* b1   = (const float*)d_in[18];
  const float* w2   = (const float*)d_in[19];
  const float* b2   = (const float*)d_in[20];
  const float* hw   = (const float*)d_in[21];
  const float* hb   = (const float*)d_in[22];

  char* p = (char*)d_ws;
  auto alloc = [&](size_t bytes) -> void* {
    void* r = (void*)p;
    p += (bytes + 255) & ~((size_t)255);
    return r;
  };
  float* x    = (float*)alloc((size_t)T * D * 4);
  float* xn   = (float*)alloc((size_t)T * D * 4);
  float* qkvb = (float*)alloc((size_t)T * 2304 * 4);
  float* att  = (float*)alloc((size_t)T * D * 4);
  float* kvp  = (float*)alloc((size_t)8 * 24 * 4160 * 4);
  float* kv   = (float*)alloc((size_t)24 * 4160 * 4);
  float* srow = (float*)alloc((size_t)T * 4 * 4);
  float* glog = (float*)alloc((size_t)T * 4 * 4);
  float* bqkv = (float*)alloc((size_t)2304 * 4);
  float* wqkv = (float*)alloc((size_t)D * 2304 * 4);
  int*   list = (int*)alloc((size_t)NE * 2048 * 4);
  int*   rnkl = (int*)alloc((size_t)NE * 2048 * 4);
  int*   cnt  = (int*)alloc((size_t)16);
  // xn planes (3 x T x 768 bf16 = 9.44 MB) overlay xn (6.3) + head of qkvb
  // (both dead at LN2 time; qkvb fully rewritten next layer).
  unsigned short* xnP = (unsigned short*)xn;
  // d_out (262.1 MB) scratch overlays, all dead before the head writes it:
  //   hseP: 3 bf16 planes x [4][2048][3072]  = 151.0 MB   @ 0
  //   xc:   8 fp32 chunk buffers x [T][768]  =  50.3 MB   @ 151.0 MB
  //   wp:   3 bf16 planes x [4][3072][768]   =  56.6 MB   @ 201.3 MB (258 MB)
  bf16* hseP = (bf16*)d_out;
  float* xc = (float*)((char*)d_out + (size_t)3 * PSH * 2);
  unsigned short* wp =
      (unsigned short*)((char*)d_out + (size_t)3 * PSH * 2 +
                        (size_t)8 * T * D * 4);
  // Head-phase overlays in ws (dead regions): xb on xn; hwT on qkvb.
  bf16* xb  = (bf16*)xn;
  bf16* hwT = (bf16*)qkvb;

  k_embed<<<dim3(6144), 256, 0, stream>>>(tokens, emb, pos, x);

  for (int l = 0; l < NL; ++l) {
    const size_t DD = (size_t)D * D;
    k_catW<<<dim3(6912), 256, 0, stream>>>(qw + l * DD, kw + l * DD,
                                           vw + l * DD, wqkv);
    k_cat3<<<dim3(9), 256, 0, stream>>>(qb + l * D, kb + l * D, vb + l * D,
                                        bqkv);

    // attention
    k_ln<<<dim3(T), 256, 0, stream>>>(x, ln1g + l * D, ln1b + l * D, xn,
                                      nullptr, nullptr, nullptr, nullptr);
    k_fgemm<1><<<dim3(18, 16, 1), 256, 0, stream>>>(
        xn, D, wqkv, 2304, bqkv, qkvb, 2304, D);
    k_kvpart<<<dim3(24, 8), 256, 0, stream>>>(qkvb, kvp);
    k_kvred<<<dim3(390), 256, 0, stream>>>(kvp, kv);
    k_attnout<<<dim3(T), 256, 0, stream>>>(qkvb, kv, att);
    k_fgemm<2><<<dim3(6, 16, 1), 256, 0, stream>>>(
        att, D, ow + l * DD, D, ob + l * D, x, D, D);

    // MoE (sparse top-2, fp32-faithful bf16x3 MFMA)
    k_ln<<<dim3(T), 256, 0, stream>>>(x, ln2g + l * D, ln2b + l * D, nullptr,
                                      xnP, gw + (size_t)l * D * NE, gb + l * NE,
                                      glog);
    k_scan<<<dim3(1), 256, 0, stream>>>(glog, srow, list, rnkl, cnt);
    k_tsplit3<<<dim3(48, 12, 4), 256, 0, stream>>>(
        w1 + (size_t)l * NE * D * DH, (long)D * DH, wp, EB, PSW, DH, D);
    k_moe3<0><<<dim3(24, 16, 4), 256, 0, stream>>>(
        (const bf16*)xnP, PSX, (const bf16*)wp, PSW, b1 + (size_t)l * NE * DH,
        hseP, nullptr, srow, list, rnkl, cnt);
    k_tsplit3<<<dim3(12, 48, 4), 256, 0, stream>>>(
        w2 + (size_t)l * NE * DH * D, (long)DH * D, wp, EB, PSW, D, DH);
    k_moe3<1><<<dim3(6, 16, 16), 256, 0, stream>>>(
        hseP, PSH, (const bf16*)wp, PSW, nullptr, nullptr, xc, srow, list,
        rnkl, cnt);
    k_moeadd<<<dim3(6144), 256, 0, stream>>>(x, xc, srow,
                                             b2 + (size_t)l * NE * D);
  }

  // ------------------------------------------------------------- head -------
  k_f2b<<<dim3(6144), 256, 0, stream>>>(x, xb);
  for (int half = 0; half < 2; ++half) {
    k_transpose<<<dim3(250, 12, 1), 256, 0, stream>>>(
        hw + half * 16000, (unsigned short*)hwT, V, D);
    k_bgemm<<<dim3(125, 16, 1), 256, 0, stream>>>(
        xb, hwT, hb + half * 16000, (float*)d_out + half * 16000, V, D);
  }
}

// Round 12
// 2659.115 us; speedup vs baseline: 4.9829x; 1.2445x over previous
//
#include <hip/hip_runtime.h>
#include <hip/hip_bf16.h>
#include <cstdint>
#include <cstddef>

typedef __hip_bfloat16 bf16;
typedef __attribute__((ext_vector_type(8))) short bf16x8;
typedef __attribute__((ext_vector_type(4))) float f32x4;

#define DEV __device__ __forceinline__

static constexpr int D  = 768;
static constexpr int NH = 12;
static constexpr int NE = 4;
static constexpr int DH = 3072;
static constexpr int L  = 1024;
static constexpr int T  = 2048;
static constexpr int V  = 32000;
static constexpr int NL = 4;

static constexpr long PSX = (long)T * 768;        // activation plane stride
static constexpr long PSH = (long)NE * 2048 * DH; // hse plane stride
static constexpr long PSW = (long)NE * DH * 768;  // MoE weight plane stride
static constexpr long PSQ = (long)2304 * 768;     // qkv weight plane stride
static constexpr long PSO = (long)768 * 768;      // o-proj weight plane stride
static constexpr long EB  = (long)DH * 768;       // per-expert weight elems

DEV float b2f(bf16 v) { return __bfloat162float(v); }
DEV bf16 f2b(float f) { return __float2bfloat16(f); }
DEV unsigned short f2bu(float f) {
  bf16 b = f2b(f);
  return *reinterpret_cast<unsigned short*>(&b);
}
DEV float gelu(float v) {
  return 0.5f * v * (1.f + erff(v * 0.70710678118654752f));
}
// Exact fp32 -> 3x bf16 plane decomposition (a ~= p0+p1+p2 to ~2^-24).
DEV void split3u(float a, unsigned short& x0, unsigned short& x1,
                 unsigned short& x2) {
  bf16 c0 = f2b(a);
  float r1 = a - b2f(c0);
  bf16 c1 = f2b(r1);
  float r2 = r1 - b2f(c1);
  bf16 c2 = f2b(r2);
  x0 = *reinterpret_cast<unsigned short*>(&c0);
  x1 = *reinterpret_cast<unsigned short*>(&c1);
  x2 = *reinterpret_cast<unsigned short*>(&c2);
}

// ---------------------------------------------------------------- staging ----
DEV void gld16(const void* g, short* ldsbase, int lane) {
#if __has_builtin(__builtin_amdgcn_global_load_lds)
  (void)lane;
  __builtin_amdgcn_global_load_lds(
      (const __attribute__((address_space(1))) unsigned int*)g,
      (__attribute__((address_space(3))) unsigned int*)ldsbase, 16, 0, 0);
#else
  *reinterpret_cast<bf16x8*>(ldsbase + lane * 8) =
      *reinterpret_cast<const bf16x8*>(g);
#endif
}

// 6-term bf16x3 MFMA accumulate macro-helper (i+j<=2 cross products).
DEV void mfma6(f32x4 acc[4][4], const bf16x8 af[3][4], const short* ldsB,
               int wn, int ln, int kg) {
#pragma unroll
  for (int c = 0; c < 4; ++c) {
    const int bo = (wn + c * 16 + ln) * 32 + kg * 8;
    const bf16x8 bv0 = *reinterpret_cast<const bf16x8*>(&ldsB[bo]);
    const bf16x8 bv1 = *reinterpret_cast<const bf16x8*>(&ldsB[4096 + bo]);
    const bf16x8 bv2 = *reinterpret_cast<const bf16x8*>(&ldsB[8192 + bo]);
#pragma unroll
    for (int r = 0; r < 4; ++r) {
      f32x4 a = acc[r][c];
      a = __builtin_amdgcn_mfma_f32_16x16x32_bf16(af[0][r], bv0, a, 0, 0, 0);
      a = __builtin_amdgcn_mfma_f32_16x16x32_bf16(af[0][r], bv1, a, 0, 0, 0);
      a = __builtin_amdgcn_mfma_f32_16x16x32_bf16(af[1][r], bv0, a, 0, 0, 0);
      a = __builtin_amdgcn_mfma_f32_16x16x32_bf16(af[0][r], bv2, a, 0, 0, 0);
      a = __builtin_amdgcn_mfma_f32_16x16x32_bf16(af[1][r], bv1, a, 0, 0, 0);
      a = __builtin_amdgcn_mfma_f32_16x16x32_bf16(af[2][r], bv0, a, 0, 0, 0);
      acc[r][c] = a;
    }
  }
}

// --------------------------------------- dense bf16x3 fp32-faithful GEMM ----
// C[2048,N] = A @ B + bias; A planes [2048][768], B^T planes [N][768], K=768.
// EPI 1: qkv (elu+1 for col<1536) -> fp32 out. EPI 2: out += acc + bias.
template <int EPI>
__global__ __launch_bounds__(256) void k_g3(
    const bf16* __restrict__ Ap, long psA,
    const bf16* __restrict__ Bp, long psB,
    const float* __restrict__ bias,
    float* __restrict__ outp, int ldc) {
  const int m0 = blockIdx.y * 128;
  const int n0 = blockIdx.x * 128;
  const int tid  = threadIdx.x;
  const int wave = tid >> 6;
  const int lane = tid & 63;
  const int wm = (wave >> 1) * 64;
  const int wn = (wave & 1) * 64;
  const int ln = lane & 15;
  const int kg = lane >> 4;
  const int rowA = lane >> 2;
  const int colK = (lane & 3) * 8;

  __shared__ short lds[24576];  // A planes @0/4096/8192, B planes @12288+

  f32x4 acc[4][4] = {};

  for (int kt = 0; kt < 768; kt += 32) {
    __syncthreads();
#pragma unroll
    for (int c2 = 0; c2 < 2; ++c2) {
      const int chunk = c2 * 4 + wave;
      const int r16 = chunk * 16 + rowA;
      const size_t arow = (size_t)(m0 + r16);
      const size_t brow = (size_t)(n0 + r16);
#pragma unroll
      for (int p = 0; p < 3; ++p) {
        gld16(Ap + (size_t)p * psA + arow * 768 + kt + colK,
              &lds[p * 4096 + chunk * 512], lane);
        gld16(Bp + (size_t)p * psB + brow * 768 + kt + colK,
              &lds[12288 + p * 4096 + chunk * 512], lane);
      }
    }
    __syncthreads();

    bf16x8 af[3][4];
#pragma unroll
    for (int r = 0; r < 4; ++r)
#pragma unroll
      for (int p = 0; p < 3; ++p)
        af[p][r] = *reinterpret_cast<const bf16x8*>(
            &lds[p * 4096 + (wm + r * 16 + ln) * 32 + kg * 8]);
    mfma6(acc, af, &lds[12288], wn, ln, kg);
  }

#pragma unroll
  for (int c = 0; c < 4; ++c) {
    const int col = n0 + wn + c * 16 + ln;
    const float bvl = bias[col];
#pragma unroll
    for (int r = 0; r < 4; ++r)
#pragma unroll
      for (int j = 0; j < 4; ++j) {
        const int row = m0 + wm + r * 16 + kg * 4 + j;
        const float v = acc[r][c][j] + bvl;
        const size_t idx = (size_t)row * ldc + col;
        if constexpr (EPI == 1) {
          outp[idx] = (col < 1536) ? (v > 0.f ? v + 1.f : expf(v)) : v;
        } else {
          outp[idx] += v;
        }
      }
  }
}

// ----------------------------------------- bf16x3 split-precision MoE GEMM --
// PH=0 (UP):  grid (24,16,4); XCD-chunked tile order (n-panel-major, m-inner)
//             so each XCD keeps its B-panels L2-resident. Gather rows via
//             list[z]; out = hse planes (gelu(acc+b1)*srow, split3).
// PH=1 (DOWN):grid (6,16,16); blockIdx.z = z*4+kc (split-K 3072 = 4x768);
//             out xc[(kc*2+rank)][tok][768] fp32.
template <int PH>
__global__ __launch_bounds__(256) void k_moe3(
    const bf16* __restrict__ Ap, long psA,
    const bf16* __restrict__ Bp, long psB,
    const float* __restrict__ b1z,
    bf16* __restrict__ hseP,
    float* __restrict__ xc,
    const float* __restrict__ srow, const int* __restrict__ list,
    const int* __restrict__ rnkl, const int* __restrict__ cnt) {
  int bx, by, z, kc;
  if constexpr (PH == 0) {
    // 1536 blocks; XCD k (= bid%8) gets tiles t in [k*192,(k+1)*192):
    // t = x*64 + z*16 + y  ->  3 n-panels per XCD, m fastest, then expert.
    const int bid =
        (blockIdx.z * gridDim.y + blockIdx.y) * gridDim.x + blockIdx.x;
    const int t = (bid & 7) * 192 + (bid >> 3);
    bx = t >> 6;
    const int rem = t & 63;
    z = rem >> 4;
    by = rem & 15;
    kc = 0;
  } else {
    bx = blockIdx.x;
    by = blockIdx.y;
    z = blockIdx.z >> 2;
    kc = blockIdx.z & 3;
  }
  const int m0 = by * 128;
  const int cz = cnt[z];
  if (m0 >= cz) return;
  const int n0 = bx * 128;
  constexpr int LD = PH ? 3072 : 768;
  const int kBeg = kc * 768;

  const int tid  = threadIdx.x;
  const int wave = tid >> 6;
  const int lane = tid & 63;
  const int wm = (wave >> 1) * 64;
  const int wn = (wave & 1) * 64;
  const int ln = lane & 15;
  const int kg = lane >> 4;
  const int rowA = lane >> 2;
  const int colK = (lane & 3) * 8;

  __shared__ short lds[24576];
  __shared__ int rows[128];
  __shared__ int rnks[128];
  if (tid < 128) {
    rows[tid] = list[z * 2048 + m0 + tid];
    if (PH == 1) rnks[tid] = rnkl[z * 2048 + m0 + tid];
  }

  f32x4 acc[4][4] = {};
  const bf16* Bz = Bp + (size_t)z * EB;

  for (int kt = kBeg; kt < kBeg + 768; kt += 32) {
    __syncthreads();
#pragma unroll
    for (int c2 = 0; c2 < 2; ++c2) {
      const int chunk = c2 * 4 + wave;
      const int r16 = chunk * 16 + rowA;
      const size_t arow =
          (PH == 0) ? (size_t)rows[r16] : (size_t)(z * 2048 + m0 + r16);
      const size_t brow = (size_t)(n0 + r16);
#pragma unroll
      for (int p = 0; p < 3; ++p) {
        gld16(Ap + (size_t)p * psA + arow * LD + kt + colK,
              &lds[p * 4096 + chunk * 512], lane);
        gld16(Bz + (size_t)p * psB + brow * LD + kt + colK,
              &lds[12288 + p * 4096 + chunk * 512], lane);
      }
    }
    __syncthreads();

    bf16x8 af[3][4];
#pragma unroll
    for (int r = 0; r < 4; ++r)
#pragma unroll
      for (int p = 0; p < 3; ++p)
        af[p][r] = *reinterpret_cast<const bf16x8*>(
            &lds[p * 4096 + (wm + r * 16 + ln) * 32 + kg * 8]);
    mfma6(acc, af, &lds[12288], wn, ln, kg);
  }

#pragma unroll
  for (int c = 0; c < 4; ++c) {
    const int col = n0 + wn + c * 16 + ln;
    float bvl = 0.f;
    if constexpr (PH == 0) bvl = b1z[z * 3072 + col];
#pragma unroll
    for (int r = 0; r < 4; ++r)
#pragma unroll
      for (int j = 0; j < 4; ++j) {
        const int rl = wm + r * 16 + kg * 4 + j;
        if constexpr (PH == 0) {
          const int pos = m0 + rl;
          const int tok = rows[rl];
          const float s = srow[tok * 4 + z];
          const float h = s * gelu(acc[r][c][j] + bvl);
          unsigned short u0, u1, u2;
          split3u(h, u0, u1, u2);
          unsigned short* hp = (unsigned short*)hseP;
          const size_t o = ((size_t)z * 2048 + pos) * 3072 + col;
          hp[o] = u0;
          hp[PSH + o] = u1;
          hp[2 * PSH + o] = u2;
        } else {
          if (m0 + rl < cz) {
            const int tok = rows[rl];
            const int rk = rnks[rl];
            xc[((size_t)(kc * 2 + rk) * T + tok) * 768 + col] = acc[r][c][j];
          }
        }
      }
  }
}

// ----------------------------------------------------- bf16 MFMA head GEMM --
__global__ __launch_bounds__(256) void k_bgemm(
    const bf16* __restrict__ A, const bf16* __restrict__ BT,
    const float* __restrict__ bias, float* __restrict__ outp,
    int ldc, int Keff) {
  const int tid  = threadIdx.x;
  const int wave = tid >> 6;
  const int lane = tid & 63;
  const int m0 = blockIdx.y * 128;
  const int n0 = blockIdx.x * 128;
  const int wm = (wave >> 1) * 64;
  const int wn = (wave & 1) * 64;
  const int ln = lane & 15;
  const int kg = lane >> 4;

  __shared__ short lds[8192];

  f32x4 acc[4][4] = {};

  const int rowA = lane >> 2;
  const int colK = (lane & 3) * 8;

  for (int kt = 0; kt < Keff; kt += 32) {
    __syncthreads();
#pragma unroll
    for (int c2 = 0; c2 < 2; ++c2) {
      const int chunk = c2 * 4 + wave;
      const int row = chunk * 16 + rowA;
      gld16(A + (size_t)(m0 + row) * 768 + kt + colK, &lds[chunk * 512], lane);
      gld16(BT + (size_t)(n0 + row) * 768 + kt + colK, &lds[4096 + chunk * 512],
            lane);
    }
    __syncthreads();

    bf16x8 af[4], bv[4];
#pragma unroll
    for (int r = 0; r < 4; ++r)
      af[r] = *reinterpret_cast<const bf16x8*>(
          &lds[(wm + r * 16 + ln) * 32 + kg * 8]);
#pragma unroll
    for (int c = 0; c < 4; ++c)
      bv[c] = *reinterpret_cast<const bf16x8*>(
          &lds[4096 + (wn + c * 16 + ln) * 32 + kg * 8]);

#pragma unroll
    for (int r = 0; r < 4; ++r)
#pragma unroll
      for (int c = 0; c < 4; ++c)
        acc[r][c] = __builtin_amdgcn_mfma_f32_16x16x32_bf16(
            af[r], bv[c], acc[r][c], 0, 0, 0);
  }

#pragma unroll
  for (int c = 0; c < 4; ++c) {
    const int nn = n0 + wn + c * 16 + ln;
    const float bvl = bias[nn];
#pragma unroll
    for (int r = 0; r < 4; ++r)
#pragma unroll
      for (int j = 0; j < 4; ++j) {
        const int mm = m0 + wm + r * 16 + kg * 4 + j;
        outp[(size_t)mm * ldc + nn] = acc[r][c][j] + bvl;
      }
  }
}

// -------------------------------------------------------------- transposes ---
// fp32 [R][C] -> bf16 [C][R] (head weights)
__global__ __launch_bounds__(256) void k_transpose(
    const float* __restrict__ in, unsigned short* __restrict__ out,
    int C, int outStride) {
  __shared__ float t[64][65];
  const int tx = threadIdx.x & 15, ty = threadIdx.x >> 4;
  const int r0 = blockIdx.y * 64, c0 = blockIdx.x * 64;
#pragma unroll
  for (int i = 0; i < 4; ++i) {
    const int r = ty + i * 16;
    const float4 v = *(const float4*)&in[(size_t)(r0 + r) * C + c0 + tx * 4];
    t[r][tx * 4 + 0] = v.x;
    t[r][tx * 4 + 1] = v.y;
    t[r][tx * 4 + 2] = v.z;
    t[r][tx * 4 + 3] = v.w;
  }
  __syncthreads();
#pragma unroll
  for (int i = 0; i < 4; ++i) {
    const int a = ty + i * 16;
    ushort4 v;
    v.x = f2bu(t[tx * 4 + 0][a]);
    v.y = f2bu(t[tx * 4 + 1][a]);
    v.z = f2bu(t[tx * 4 + 2][a]);
    v.w = f2bu(t[tx * 4 + 3][a]);
    *(ushort4*)&out[(size_t)(c0 + a) * outStride + r0 + tx * 4] = v;
  }
}

// fp32 [R][C] -> 3x bf16 planes [C][R], z batches (experts).
__global__ __launch_bounds__(256) void k_tsplit3(
    const float* __restrict__ in, long inE,
    unsigned short* __restrict__ out, long outE, long planeS,
    int C, int outStride) {
  in += (size_t)blockIdx.z * inE;
  unsigned short* o = out + (size_t)blockIdx.z * outE;
  __shared__ float t[64][65];
  const int tx = threadIdx.x & 15, ty = threadIdx.x >> 4;
  const int r0 = blockIdx.y * 64, c0 = blockIdx.x * 64;
#pragma unroll
  for (int i = 0; i < 4; ++i) {
    const int r = ty + i * 16;
    const float4 v = *(const float4*)&in[(size_t)(r0 + r) * C + c0 + tx * 4];
    t[r][tx * 4 + 0] = v.x;
    t[r][tx * 4 + 1] = v.y;
    t[r][tx * 4 + 2] = v.z;
    t[r][tx * 4 + 3] = v.w;
  }
  __syncthreads();
#pragma unroll
  for (int i = 0; i < 4; ++i) {
    const int a = ty + i * 16;
    ushort4 u0, u1, u2;
    split3u(t[tx * 4 + 0][a], u0.x, u1.x, u2.x);
    split3u(t[tx * 4 + 1][a], u0.y, u1.y, u2.y);
    split3u(t[tx * 4 + 2][a], u0.z, u1.z, u2.z);
    split3u(t[tx * 4 + 3][a], u0.w, u1.w, u2.w);
    const size_t off = (size_t)(c0 + a) * outStride + r0 + tx * 4;
    *(ushort4*)&o[off] = u0;
    *(ushort4*)&o[planeS + off] = u1;
    *(ushort4*)&o[2 * planeS + off] = u2;
  }
}

// ------------------------------------------------------------ small kernels --
__global__ void k_embed(const int* __restrict__ tok,
                        const float* __restrict__ emb,
                        const float* __restrict__ pos, float* __restrict__ x) {
  const int idx = blockIdx.x * 256 + threadIdx.x;
  const int t = idx / D, d = idx - t * D;
  const int tk = tok[t];
  x[idx] = emb[(size_t)tk * D + d] + pos[(size_t)(t & (L - 1)) * D + d];
}

__global__ void k_f2b(const float* __restrict__ x, bf16* __restrict__ o) {
  const int idx = blockIdx.x * 256 + threadIdx.x;
  o[idx] = f2b(x[idx]);
}

// LayerNorm fp32 in -> 3x bf16 planes out; optional fp32 gate logits (+gb).
__global__ __launch_bounds__(256) void k_ln(const float* __restrict__ x,
                                            const float* __restrict__ g,
                                            const float* __restrict__ bb,
                                            unsigned short* __restrict__ xnp,
                                            const float* __restrict__ gw,
                                            const float* __restrict__ gb,
                                            float* __restrict__ glog) {
  const int row = blockIdx.x, tid = threadIdx.x;
  const float* xr = x + (size_t)row * D;
  const float v0 = xr[tid], v1 = xr[tid + 256], v2 = xr[tid + 512];
  float s = v0 + v1 + v2, s2 = v0 * v0 + v1 * v1 + v2 * v2;
  for (int off = 1; off < 64; off <<= 1) {
    s += __shfl_xor(s, off);
    s2 += __shfl_xor(s2, off);
  }
  __shared__ float rs[4], rs2[4];
  const int w = tid >> 6;
  if ((tid & 63) == 0) { rs[w] = s; rs2[w] = s2; }
  __syncthreads();
  const float S = rs[0] + rs[1] + rs[2] + rs[3];
  const float S2 = rs2[0] + rs2[1] + rs2[2] + rs2[3];
  const float mean = S * (1.f / 768.f);
  const float var = fmaxf(S2 * (1.f / 768.f) - mean * mean, 0.f);
  const float rstd = rsqrtf(var + 1e-5f);
  const float o0 = (v0 - mean) * rstd * g[tid]       + bb[tid];
  const float o1 = (v1 - mean) * rstd * g[tid + 256] + bb[tid + 256];
  const float o2 = (v2 - mean) * rstd * g[tid + 512] + bb[tid + 512];
  {
    const size_t base = (size_t)row * D;
    unsigned short a0, a1, a2;
    split3u(o0, a0, a1, a2);
    xnp[base + tid] = a0;
    xnp[PSX + base + tid] = a1;
    xnp[2 * PSX + base + tid] = a2;
    split3u(o1, a0, a1, a2);
    xnp[base + tid + 256] = a0;
    xnp[PSX + base + tid + 256] = a1;
    xnp[2 * PSX + base + tid + 256] = a2;
    split3u(o2, a0, a1, a2);
    xnp[base + tid + 512] = a0;
    xnp[PSX + base + tid + 512] = a1;
    xnp[2 * PSX + base + tid + 512] = a2;
  }

  if (gw != nullptr) {
    const float4 ga = *(const float4*)&gw[tid * 4];
    const float4 gbv = *(const float4*)&gw[(tid + 256) * 4];
    const float4 gc = *(const float4*)&gw[(tid + 512) * 4];
    float p0 = o0 * ga.x + o1 * gbv.x + o2 * gc.x;
    float p1 = o0 * ga.y + o1 * gbv.y + o2 * gc.y;
    float p2 = o0 * ga.z + o1 * gbv.z + o2 * gc.z;
    float p3 = o0 * ga.w + o1 * gbv.w + o2 * gc.w;
    for (int off = 1; off < 64; off <<= 1) {
      p0 += __shfl_xor(p0, off);
      p1 += __shfl_xor(p1, off);
      p2 += __shfl_xor(p2, off);
      p3 += __shfl_xor(p3, off);
    }
    __shared__ float rg[4][4];
    if ((tid & 63) == 0) {
      rg[w][0] = p0; rg[w][1] = p1; rg[w][2] = p2; rg[w][3] = p3;
    }
    __syncthreads();
    if (tid == 0) {
      float* gl = glog + (size_t)row * 4;
#pragma unroll
      for (int e = 0; e < 4; ++e)
        gl[e] = rg[0][e] + rg[1][e] + rg[2][e] + rg[3][e] + gb[e];
    }
  }
}

// top-2 softmax weights + deterministic per-expert token lists.
__global__ __launch_bounds__(256) void k_scan(const float* __restrict__ glog,
                                              float* __restrict__ srow,
                                              int* __restrict__ list,
                                              int* __restrict__ rnkl,
                                              int* __restrict__ cnt) {
  const int tid = threadIdx.x;
  __shared__ unsigned char e1s[2048], e2s[2048];
  for (int t = tid; t < T; t += 256) {
    float gv[4];
#pragma unroll
    for (int i = 0; i < 4; ++i) gv[i] = glog[t * 4 + i];
    int i1 = 0;
#pragma unroll
    for (int i = 1; i < 4; ++i)
      if (gv[i] > gv[i1]) i1 = i;
    int i2 = -1;
#pragma unroll
    for (int i = 0; i < 4; ++i) {
      if (i == i1) continue;
      if (i2 < 0 || gv[i] > gv[i2]) i2 = i;
    }
    const float e = expf(gv[i2] - gv[i1]);
    const float wa = 1.f / (1.f + e), wb = e / (1.f + e);
    float o[4] = {0.f, 0.f, 0.f, 0.f};
    o[i1] = wa;
    o[i2] = wb;
#pragma unroll
    for (int i = 0; i < 4; ++i) srow[t * 4 + i] = o[i];
    e1s[t] = (unsigned char)i1;
    e2s[t] = (unsigned char)i2;
  }
  __syncthreads();
  const int w = tid >> 6, lane = tid & 63;
  int base = 0;
  for (int c = 0; c < 32; ++c) {
    const int t = c * 64 + lane;
    const bool f1 = (e1s[t] == w);
    const bool f2 = (e2s[t] == w);
    const bool f = f1 || f2;
    const unsigned long long mask = __ballot(f);
    const int mypos = __popcll(mask & ((1ull << lane) - 1ull));
    if (f) {
      list[w * 2048 + base + mypos] = t;
      rnkl[w * 2048 + base + mypos] = f1 ? 0 : 1;
    }
    base += __popcll(mask);
  }
  if (lane == 0) cnt[w] = base;
  for (int ppos = base + lane; ppos < 2048; ppos += 64) {
    list[w * 2048 + ppos] = 0;
    rnkl[w * 2048 + ppos] = 0;
  }
}

// x += sum_{c=0..7} xc[c] + sum_e srow[t][e] * b2[e][n]  (fixed order)
__global__ void k_moeadd(float* __restrict__ x, const float* __restrict__ xc,
                         const float* __restrict__ srow,
                         const float* __restrict__ b2l) {
  const int idx = blockIdx.x * 256 + threadIdx.x;
  const int t = idx / D, n = idx - t * D;
  const float* s = srow + t * 4;
  float acc = x[idx];
#pragma unroll
  for (int c = 0; c < 8; ++c) acc += xc[(size_t)c * T * D + idx];
  acc += s[0] * b2l[n] + s[1] * b2l[D + n] + s[2] * b2l[2 * D + n] +
         s[3] * b2l[3 * D + n];
  x[idx] = acc;
}

__global__ void k_cat3(const float* __restrict__ a, const float* __restrict__ b,
                       const float* __restrict__ c, float* __restrict__ o) {
  const int i = blockIdx.x * 256 + threadIdx.x;
  o[i] = i < 768 ? a[i] : (i < 1536 ? b[i - 768] : c[i - 1536]);
}

// Partial KV/Z over an L-chunk of 128 rows. part[c][bh][e*64+f], Z at +4096.
__global__ __launch_bounds__(256) void k_kvpart(const float* __restrict__ qkv,
                                                float* __restrict__ part) {
  const int bh = blockIdx.x;
  const int b = bh / NH, h = bh % NH;
  const int c = blockIdx.y;
  const int tid = threadIdx.x;
  __shared__ float kf[64], vv[64];
  float acc[16];
#pragma unroll
  for (int j = 0; j < 16; ++j) acc[j] = 0.f;
  float zacc = 0.f;
  const int e = tid >> 2;
  const int f0 = (tid & 3) * 16;
  const int t0 = b * L + c * 128;
  for (int i = 0; i < 128; ++i) {
    __syncthreads();
    const size_t rowb = (size_t)(t0 + i) * 2304;
    if (tid < 64) kf[tid] = qkv[rowb + 768 + h * 64 + tid];
    else if (tid < 128) vv[tid - 64] = qkv[rowb + 1536 + h * 64 + (tid - 64)];
    __syncthreads();
    const float ke = kf[e];
#pragma unroll
    for (int j = 0; j < 16; ++j) acc[j] += ke * vv[f0 + j];
    if (tid < 64) zacc += kf[tid];
  }
  const size_t base = ((size_t)c * 24 + bh) * 4160;
#pragma unroll
  for (int j = 0; j < 16; ++j) part[base + e * 64 + f0 + j] = acc[j];
  if (tid < 64) part[base + 4096 + tid] = zacc;
}

__global__ void k_kvred(const float* __restrict__ part, float* __restrict__ kv) {
  const int idx = blockIdx.x * 256 + threadIdx.x;
  float s = 0.f;
#pragma unroll
  for (int cc = 0; cc < 8; ++cc) s += part[(size_t)cc * 99840 + idx];
  kv[idx] = s;
}

// attention apply; emits 3-plane bf16x3 output for the o-proj g3 GEMM.
__global__ __launch_bounds__(256) void k_attnout(
    const float* __restrict__ qkv, const float* __restrict__ kv,
    unsigned short* __restrict__ attP) {
  const int t = blockIdx.x;
  const int b = t >> 10;
  const int tid = threadIdx.x;
  __shared__ float q[768];
  __shared__ float den[12];
  for (int i = tid; i < 768; i += 256) q[i] = qkv[(size_t)t * 2304 + i];
  __syncthreads();
  if (tid < 12) {
    const float* zz = kv + ((size_t)(b * NH + tid)) * 4160 + 4096;
    float s = 0.f;
#pragma unroll
    for (int e = 0; e < 64; ++e) s += q[tid * 64 + e] * zz[e];
    den[tid] = s + 1e-6f;
  }
  __syncthreads();
  for (int i = tid; i < 768; i += 256) {
    const int h = i >> 6, f = i & 63;
    const float* Kv = kv + ((size_t)(b * NH + h)) * 4160;
    float s = 0.f;
#pragma unroll
    for (int e = 0; e < 64; ++e) s += q[h * 64 + e] * Kv[e * 64 + f];
    const float r = s / den[h];
    unsigned short u0, u1, u2;
    split3u(r, u0, u1, u2);
    const size_t o = (size_t)t * 768 + i;
    attP[o] = u0;
    attP[PSX + o] = u1;
    attP[2 * PSX + o] = u2;
  }
}

// ------------------------------------------------------------------ launch ---
extern "C" void kernel_launch(void* const* d_in, const int* in_sizes, int n_in,
                              void* d_out, int out_size, void* d_ws,
                              size_t ws_size, hipStream_t stream) {
  const int*   tokens = (const int*)d_in[0];
  const float* emb  = (const float*)d_in[1];
  const float* pos  = (const float*)d_in[2];
  const float* qw   = (const float*)d_in[3];
  const float* qb   = (const float*)d_in[4];
  const float* kw   = (const float*)d_in[5];
  const float* kb   = (const float*)d_in[6];
  const float* vw   = (const float*)d_in[7];
  const float* vb   = (const float*)d_in[8];
  const float* ow   = (const float*)d_in[9];
  const float* ob   = (const float*)d_in[10];
  const float* ln1g = (const float*)d_in[11];
  const float* ln1b = (const float*)d_in[12];
  const float* ln2g = (const float*)d_in[13];
  const float* ln2b = (const float*)d_in[14];
  const float* gw   = (const float*)d_in[15];
  const float* gb   = (const float*)d_in[16];
  const float* w1   = (const float*)d_in[17];
  const float* b1   = (const float*)d_in[18];
  const float* w2   = (const float*)d_in[19];
  const float* b2   = (const float*)d_in[20];
  const float* hw   = (const float*)d_in[21];
  const float* hb   = (const float*)d_in[22];

  char* p = (char*)d_ws;
  auto alloc = [&](size_t bytes) -> void* {
    void* r = (void*)p;
    p += (bytes + 255) & ~((size_t)255);
    return r;
  };
  float* x    = (float*)alloc((size_t)T * D * 4);          // 6.3 MB
  float* xn   = (float*)alloc((size_t)T * D * 4);          // 6.3 MB (head xb)
  float* qkvb = (float*)alloc((size_t)T * 2304 * 4);       // 18.9 MB
  float* att  = (float*)alloc((size_t)T * D * 4);          // 6.3 MB \ pbuf
  float* kvp  = (float*)alloc((size_t)8 * 24 * 4160 * 4);  // 3.2 MB / 9.49 MB
  float* kv   = (float*)alloc((size_t)24 * 4160 * 4);
  float* srow = (float*)alloc((size_t)T * 4 * 4);
  float* glog = (float*)alloc((size_t)T * 4 * 4);
  float* bqkv = (float*)alloc((size_t)2304 * 4);
  int*   list = (int*)alloc((size_t)NE * 2048 * 4);
  int*   rnkl = (int*)alloc((size_t)NE * 2048 * 4);
  int*   cnt  = (int*)alloc((size_t)16);
  // Shared activation-plane buffer (3 x T x 768 bf16 = 9.44 MB) overlays
  // att+kvp (9.49 MB, both dead at each use point; strict sequential reuse:
  // LN1-planes -> qkv g3; att-planes (attnout) -> o-proj g3; LN2-planes -> UP).
  unsigned short* pbuf = (unsigned short*)att;
  // d_out (262.1 MB) scratch overlays, all dead before the head writes it:
  //   hseP @0: 3 planes x [4][2048][3072] bf16 = 151.0 MB
  //   xc   @151.0: 8 fp32 buffers x [T][768]   =  50.3 MB
  //   wp   @201.3: weight planes slot          <= 56.6 MB
  //     (per layer, sequentially: wqkvP 10.6 + owP 3.5 -> then w1/w2 planes)
  bf16* hseP = (bf16*)d_out;
  float* xc = (float*)((char*)d_out + (size_t)3 * PSH * 2);
  unsigned short* wp =
      (unsigned short*)((char*)d_out + (size_t)3 * PSH * 2 +
                        (size_t)8 * T * D * 4);
  unsigned short* wqkvP = wp;                       // 3 planes x [2304][768]
  unsigned short* owP   = wp + (size_t)3 * PSQ;     // 3 planes x [768][768]
  // Head-phase overlays (dead regions): xb on xn; hwT on qkvb+att.
  bf16* xb  = (bf16*)xn;
  bf16* hwT = (bf16*)qkvb;

  k_embed<<<dim3(6144), 256, 0, stream>>>(tokens, emb, pos, x);

  for (int l = 0; l < NL; ++l) {
    const size_t DD = (size_t)D * D;
    // attention weight planes: qw/kw/vw -> wqkvP rows 0/768/1536; ow -> owP
    k_tsplit3<<<dim3(12, 12, 1), 256, 0, stream>>>(qw + l * DD, 0, wqkvP, 0,
                                                   PSQ, D, D);
    k_tsplit3<<<dim3(12, 12, 1), 256, 0, stream>>>(
        kw + l * DD, 0, wqkvP + (size_t)768 * 768, 0, PSQ, D, D);
    k_tsplit3<<<dim3(12, 12, 1), 256, 0, stream>>>(
        vw + l * DD, 0, wqkvP + (size_t)1536 * 768, 0, PSQ, D, D);
    k_tsplit3<<<dim3(12, 12, 1), 256, 0, stream>>>(ow + l * DD, 0, owP, 0,
                                                   PSO, D, D);
    k_cat3<<<dim3(9), 256, 0, stream>>>(qb + l * D, kb + l * D, vb + l * D,
                                        bqkv);

    // attention (bf16x3 fp32-faithful GEMMs)
    k_ln<<<dim3(T), 256, 0, stream>>>(x, ln1g + l * D, ln1b + l * D, pbuf,
                                      nullptr, nullptr, nullptr);
    k_g3<1><<<dim3(18, 16, 1), 256, 0, stream>>>(
        (const bf16*)pbuf, PSX, (const bf16*)wqkvP, PSQ, bqkv, qkvb, 2304);
    k_kvpart<<<dim3(24, 8), 256, 0, stream>>>(qkvb, kvp);
    k_kvred<<<dim3(390), 256, 0, stream>>>(kvp, kv);
    k_attnout<<<dim3(T), 256, 0, stream>>>(qkvb, kv, pbuf);
    k_g3<2><<<dim3(6, 16, 1), 256, 0, stream>>>(
        (const bf16*)pbuf, PSX, (const bf16*)owP, PSO, ob + l * D, x, D);

    // MoE (sparse top-2, bf16x3 MFMA; UP XCD-chunked, DOWN split-K)
    k_ln<<<dim3(T), 256, 0, stream>>>(x, ln2g + l * D, ln2b + l * D, pbuf,
                                      gw + (size_t)l * D * NE, gb + l * NE,
                                      glog);
    k_scan<<<dim3(1), 256, 0, stream>>>(glog, srow, list, rnkl, cnt);
    k_tsplit3<<<dim3(48, 12, 4), 256, 0, stream>>>(
        w1 + (size_t)l * NE * D * DH, (long)D * DH, wp, EB, PSW, DH, D);
    k_moe3<0><<<dim3(24, 16, 4), 256, 0, stream>>>(
        (const bf16*)pbuf, PSX, (const bf16*)wp, PSW, b1 + (size_t)l * NE * DH,
        hseP, nullptr, srow, list, rnkl, cnt);
    k_tsplit3<<<dim3(12, 48, 4), 256, 0, stream>>>(
        w2 + (size_t)l * NE * DH * D, (long)DH * D, wp, EB, PSW, D, DH);
    k_moe3<1><<<dim3(6, 16, 16), 256, 0, stream>>>(
        hseP, PSH, (const bf16*)wp, PSW, nullptr, nullptr, xc, srow, list,
        rnkl, cnt);
    k_moeadd<<<dim3(6144), 256, 0, stream>>>(x, xc, srow,
                                             b2 + (size_t)l * NE * D);
  }

  // ------------------------------------------------------------- head -------
  k_f2b<<<dim3(6144), 256, 0, stream>>>(x, xb);
  for (int half = 0; half < 2; ++half) {
    k_transpose<<<dim3(250, 12, 1), 256, 0, stream>>>(
        hw + half * 16000, (unsigned short*)hwT, V, D);
    k_bgemm<<<dim3(125, 16, 1), 256, 0, stream>>>(
        xb, hwT, hb + half * 16000, (float*)d_out + half * 16000, V, D);
  }
}